// Round 16
// baseline (1792.412 us; speedup 1.0000x reference)
//
#include <hip/hip_runtime.h>
#include <hip/hip_bf16.h>

#define NN 16384
#define NE 131072
#define L 256
#define SSTEPS 4
#define OUTD 128

typedef __attribute__((ext_vector_type(8))) short bf16x8;
typedef __attribute__((ext_vector_type(4))) float f32x4;

typedef const unsigned __attribute__((address_space(1)))* as1_u32p;
typedef unsigned __attribute__((address_space(3)))* as3_u32p;

__device__ __forceinline__ void gload16(const void* g, void* lds) {
  __builtin_amdgcn_global_load_lds((as1_u32p)g, (as3_u32p)lds, 16, 0, 0);
}

__device__ __forceinline__ short f2bs(float f) {
  unsigned u = __builtin_bit_cast(unsigned, f);
  u = (u + 0x7fffu + ((u >> 16) & 1u)) >> 16;
  return (short)u;
}
__device__ __forceinline__ float bs2f(short s) {
  unsigned u = ((unsigned)(unsigned short)s) << 16;
  return __builtin_bit_cast(float, u);
}
__device__ __forceinline__ unsigned cvt_pk_bf16(float lo, float hi) {
  unsigned r;
  asm("v_cvt_pk_bf16_f32 %0, %1, %2" : "=v"(r) : "v"(lo), "v"(hi));
  return r;
}
__device__ __forceinline__ bf16x8 pack_bf16x8(const float v[8]) {
  union { unsigned u[4]; bf16x8 b; } r;
#pragma unroll
  for (int k = 0; k < 4; ++k) r.u[k] = cvt_pk_bf16(v[2 * k], v[2 * k + 1]);
  return r.b;
}

// Store one 16x16 C-tile (f32x4 per lane) into swizzled bf16 LDS [R][256]
// (row stride 512B). byte ^= (row&7)<<4.
__device__ __forceinline__ void store_tile(short* hs, int l, int mi, int nb,
                                           f32x4 v) {
  const int lm = l & 15, g = l >> 4;
#pragma unroll
  for (int i = 0; i < 4; ++i) {
    const float part = __shfl_xor(v[i], 1);
    if ((l & 1) == 0) {
      const int row = mi * 16 + g * 4 + i;
      const int col = nb + lm;  // even
      const int off = (row * 512 + col * 2) ^ ((row & 7) << 4);
      *(unsigned*)((char*)hs + off) = cvt_pk_bf16(v[i], part);
    }
  }
}

// GEMM from swizzled bf16 LDS tile (row stride AST bytes) x packed W.
template <int MI, int NT, int KC, int AST>
__device__ __forceinline__ void gemm_lds(const short* __restrict__ Wp,
                                         int Ncols, const short* hs, int n0,
                                         int l, f32x4 acc[MI][NT]) {
  const int lm = l & 15, g = l >> 4;
#pragma unroll
  for (int kc = 0; kc < KC; ++kc) {
    bf16x8 a[MI];
#pragma unroll
    for (int mi = 0; mi < MI; ++mi) {
      const int row = mi * 16 + lm;
      const int off = (row * AST + kc * 64 + g * 16) ^ ((row & 7) << 4);
      a[mi] = *(const bf16x8*)((const char*)hs + off);
    }
#pragma unroll
    for (int ni = 0; ni < NT; ++ni) {
      const int n = n0 + ni * 16 + lm;
      bf16x8 b = *(const bf16x8*)(Wp + ((size_t)kc * Ncols + n) * 32 + g * 8);
#pragma unroll
      for (int mi = 0; mi < MI; ++mi)
        acc[mi][ni] =
            __builtin_amdgcn_mfma_f32_16x16x32_bf16(a[mi], b, acc[mi][ni], 0, 0, 0);
    }
  }
}

// Pack fp32 weight [K][N] (cnt stacked) into bf16 Wp[k/32][n][k%32].
__global__ void pack_w(const float* __restrict__ src, short* __restrict__ dst,
                       int K, int N, int cnt) {
  const size_t total = (size_t)K * N * cnt;
  for (size_t i = (size_t)blockIdx.x * blockDim.x + threadIdx.x; i < total;
       i += (size_t)gridDim.x * blockDim.x) {
    const size_t mat = i / ((size_t)K * N);
    const int rem = (int)(i - mat * (size_t)K * N);
    const int k = rem / N, n = rem - k * N;
    dst[mat * (size_t)K * N + ((size_t)(k >> 5) * N + n) * 32 + (k & 31)] =
        f2bs(src[i]);
  }
}

// Pack fp32 W0 [Kreal][256] into zero-padded bf16 [256][32] (K=32 fragment).
__global__ void pack_w0_pad(const float* __restrict__ src,
                            short* __restrict__ dst, int Kreal) {
  const int i = blockIdx.x * 256 + threadIdx.x;
  if (i >= 256 * 32) return;
  const int n = i >> 5, k = i & 31;
  dst[n * 32 + k] = (k < Kreal) ? f2bs(src[k * 256 + n]) : (short)0;
}

// ---------------------------------------------------------------------------
// Async staging: [32][256] bf16 tile (16KB) from 32 consecutive global rows.
// Source byte pre-XOR'd with (row&7)<<4; LDS linear (m173 both-sides rule).
// ---------------------------------------------------------------------------
__device__ __forceinline__ void stage_tile256(const short* __restrict__ src0,
                                              short* As, int w, int l) {
#pragma unroll
  for (int i = 0; i < 4; ++i) {
    const int rbase = w * 8 + i * 2;
    const int r = rbase + (l >> 5);
    const int boff = ((l & 31) * 16) ^ ((r & 7) << 4);
    gload16((const char*)(src0 + (size_t)r * L) + boff, As + rbase * 256);
  }
}

// BM=16 variant: stage cols 0..255 (bytes [0,512) of each 1024B row) of a
// [16][512] tile; lanes 0..31 active. Upper half produced in-kernel.
__device__ __forceinline__ void stage_nodes_half16(
    const short* __restrict__ a_src, short* As, int w, int l, int n0) {
#pragma unroll
  for (int i = 0; i < 4; ++i) {
    const int r = w * 4 + i;
    if (l < 32) {
      const int cb = (l * 16) ^ ((r & 7) << 4);
      gload16((const char*)(a_src + (size_t)(n0 + r) * L) + cb, As + r * 512);
    }
  }
}

// NS/NR register gathers for two edge rows (tr, 16+tr) of a 32-edge tile.
__device__ __forceinline__ void issue_gathers(
    const short* __restrict__ NSb, const short* __restrict__ NRb, int sn0,
    int sn1, int rc0, int rc1, int seg, bf16x8 gn[2][2], bf16x8 gr[2][2]) {
  const short* p0 = NSb + (size_t)sn0 * L + seg * 8;
  gn[0][0] = *(const bf16x8*)p0;
  gn[0][1] = *(const bf16x8*)(p0 + 128);
  const short* p1 = NSb + (size_t)sn1 * L + seg * 8;
  gn[1][0] = *(const bf16x8*)p1;
  gn[1][1] = *(const bf16x8*)(p1 + 128);
  const short* q0 = NRb + (size_t)rc0 * L + seg * 8;
  gr[0][0] = *(const bf16x8*)q0;
  gr[0][1] = *(const bf16x8*)(q0 + 128);
  const short* q1 = NRb + (size_t)rc1 * L + seg * 8;
  gr[1][0] = *(const bf16x8*)q1;
  gr[1][1] = *(const bf16x8*)(q1 + 128);
}

// ---------------------------------------------------------------------------
// CSR build (deterministic: per-node lists sorted ascending by edge id).
// elist becomes the edge PERMUTATION: edge state lives in CSR order.
// ---------------------------------------------------------------------------
__global__ void csr_hist(const int* __restrict__ recv, int* __restrict__ deg) {
  const int e = blockIdx.x * 256 + threadIdx.x;
  atomicAdd(&deg[recv[e]], 1);
}
__global__ __launch_bounds__(256) void csr_scan(const int* __restrict__ deg,
                                                int* __restrict__ start,
                                                int* __restrict__ cursor) {
  __shared__ int part[256];
  const int t = threadIdx.x;
  int s = 0;
  for (int i = 0; i < NN / 256; ++i) s += deg[t * (NN / 256) + i];
  part[t] = s;
  __syncthreads();
  if (t == 0) {
    int acc = 0;
    for (int i = 0; i < 256; ++i) {
      const int v = part[i];
      part[i] = acc;
      acc += v;
    }
  }
  __syncthreads();
  int acc = part[t];
  for (int i = 0; i < NN / 256; ++i) {
    const int n = t * (NN / 256) + i;
    start[n] = acc;
    cursor[n] = acc;
    acc += deg[n];
  }
  if (t == 255) start[NN] = acc;
}
__global__ void csr_scatter(const int* __restrict__ recv,
                            int* __restrict__ cursor, int* __restrict__ elist) {
  const int e = blockIdx.x * 256 + threadIdx.x;
  const int p = atomicAdd(&cursor[recv[e]], 1);
  elist[p] = e;
}
__global__ void csr_sort(const int* __restrict__ start, int* __restrict__ elist) {
  const int n = blockIdx.x * blockDim.x + threadIdx.x;
  if (n >= NN) return;
  const int b = start[n], e = start[n + 1];
  for (int i = b + 1; i < e; ++i) {
    const int v = elist[i];
    int j = i - 1;
    while (j >= b && elist[j] > v) {
      elist[j + 1] = elist[j];
      --j;
    }
    elist[j + 1] = v;
  }
}
// permuted sender/receiver arrays: s/r of the edge at permuted position p
__global__ void permute_se(const int* __restrict__ elist,
                           const int* __restrict__ senders,
                           const int* __restrict__ receivers,
                           int* __restrict__ sn_p, int* __restrict__ rc_p) {
  const int p = blockIdx.x * 256 + threadIdx.x;
  const int e = elist[p];
  sn_p[p] = senders[e];
  rc_p[p] = receivers[e];
}

// ---------------------------------------------------------------------------
// Epilogue LN helpers
// ---------------------------------------------------------------------------
__device__ __forceinline__ void ln_row(const short* smem, int row, int seg,
                                       const float lsv[16], const float lbv[16],
                                       float ne[16]) {
  const int off0 = (row * 512 + seg * 16) ^ ((row & 7) << 4);
  const int off1 = (row * 512 + 256 + seg * 16) ^ ((row & 7) << 4);
  const bf16x8 y0 = *(const bf16x8*)((const char*)smem + off0);
  const bf16x8 y1 = *(const bf16x8*)((const char*)smem + off1);
  float v[16];
#pragma unroll
  for (int k = 0; k < 8; ++k) {
    v[k] = bs2f(y0[k]);
    v[8 + k] = bs2f(y1[k]);
  }
  float s = 0.f;
#pragma unroll
  for (int k = 0; k < 16; ++k) s += v[k];
#pragma unroll
  for (int o = 1; o < 16; o <<= 1) s += __shfl_xor(s, o);
  const float mu = s * (1.f / 256.f);
  float sq = 0.f;
#pragma unroll
  for (int k = 0; k < 16; ++k) {
    const float d = v[k] - mu;
    sq += d * d;
  }
#pragma unroll
  for (int o = 1; o < 16; o <<= 1) sq += __shfl_xor(sq, o);
  const float rstd = rsqrtf(sq * (1.f / 256.f) + 1e-6f);
#pragma unroll
  for (int k = 0; k < 16; ++k) ne[k] = (v[k] - mu) * rstd * lsv[k] + lbv[k];
}

__device__ __forceinline__ void load16(const float* __restrict__ p, int seg,
                                       float d[16]) {
  const float4 a0 = *(const float4*)(p + seg * 8);
  const float4 a1 = *(const float4*)(p + seg * 8 + 4);
  const float4 a2 = *(const float4*)(p + 128 + seg * 8);
  const float4 a3 = *(const float4*)(p + 128 + seg * 8 + 4);
  d[0] = a0.x; d[1] = a0.y; d[2] = a0.z; d[3] = a0.w;
  d[4] = a1.x; d[5] = a1.y; d[6] = a1.z; d[7] = a1.w;
  d[8] = a2.x; d[9] = a2.y; d[10] = a2.z; d[11] = a2.w;
  d[12] = a3.x; d[13] = a3.y; d[14] = a3.z; d[15] = a3.w;
}

// ---------------------------------------------------------------------------
// Projection (step 0 only): P = nodes_b @ W0_panel (K=256) -> bf16 [NN][256].
// blockIdx.y: 0 -> sender panel, 1 -> receiver panel.
// ---------------------------------------------------------------------------
__global__ __launch_bounds__(256, 4) void proj_mfma(
    const short* __restrict__ nodes_b, const short* __restrict__ Wfull,
    short* __restrict__ NSb, short* __restrict__ NRb) {
  __shared__ char smem[16384];
  short* As = (short*)smem;
  const int t = threadIdx.x, w = t >> 6, l = t & 63;
  const int tr = t >> 4, seg = t & 15;
  const int n0 = blockIdx.x * 32;
  const short* Wp = Wfull + (size_t)(8 + blockIdx.y * 8) * 256 * 32;
  short* out = blockIdx.y ? NRb : NSb;

  stage_tile256(nodes_b + (size_t)n0 * L, As, w, l);
  __syncthreads();

  f32x4 acc[2][4] = {};
  gemm_lds<2, 4, 8, 512>(Wp, L, As, w * 64, l, acc);
  __syncthreads();
#pragma unroll
  for (int ni = 0; ni < 4; ++ni)
#pragma unroll
    for (int mi = 0; mi < 2; ++mi)
      store_tile(As, l, mi, w * 64 + ni * 16, acc[mi][ni]);
  __syncthreads();

#pragma unroll
  for (int p = 0; p < 2; ++p) {
    const int row = p * 16 + tr;
    const int off0 = (row * 512 + seg * 16) ^ ((row & 7) << 4);
    const int off1 = (row * 512 + 256 + seg * 16) ^ ((row & 7) << 4);
    *(bf16x8*)(out + (size_t)(n0 + row) * L + seg * 8) =
        *(const bf16x8*)((const char*)As + off0);
    *(bf16x8*)(out + (size_t)(n0 + row) * L + 128 + seg * 8) =
        *(const bf16x8*)((const char*)As + off1);
  }
}

// ---------------------------------------------------------------------------
// Edge step (CSR-ordered edges; TWO 32-edge tiles per block, software-
// pipelined: tile t+1's stage + index loads + NS/NR gathers are issued after
// tile t's post-y barrier, hiding them under tile t's LN/store epilogue).
// XCD-bijective block swizzle (2048 blocks % 8 == 0) for NR/edge L2 locality.
// launch_bounds (256,4): (256,5) squeezed VGPR to 48 and broke the gather
// overlap (r12 post-mortem).
// ---------------------------------------------------------------------------
__global__ __launch_bounds__(256, 4) void edge_step_mfma(
    const short* __restrict__ NSb, const short* __restrict__ NRb,
    short* __restrict__ edges_b, short* __restrict__ new_e,
    const int* __restrict__ senders, const int* __restrict__ receivers,
    const short* __restrict__ W0p, const float* __restrict__ b0,
    const short* __restrict__ W1p, const float* __restrict__ b1,
    const float* __restrict__ ls, const float* __restrict__ lb) {
  __shared__ char smem[32768];
  short* As = (short*)smem;               // [32][256] staged edges; later h
  short* nsrB = (short*)(smem + 16384);   // [32][256] bf16 NS+NR; later y
  const int t = threadIdx.x, w = t >> 6, l = t & 63;
  const int lm = l & 15, g = l >> 4;
  const int tr = t >> 4, seg = t & 15;
  // XCD chunked swizzle: consecutive logical blocks land on one XCD
  const int lbid = ((blockIdx.x & 7) << 8) + (blockIdx.x >> 3);
  const int ebase = lbid * 64;

  // prologue: tile 0 indices, stage, gathers (no LDS dependency)
  int sn0 = senders[ebase + tr], rc0 = receivers[ebase + tr];
  int sn1 = senders[ebase + 16 + tr], rc1 = receivers[ebase + 16 + tr];
  stage_tile256(edges_b + (size_t)ebase * L, As, w, l);
  bf16x8 gn[2][2], gr[2][2];
  issue_gathers(NSb, NRb, sn0, sn1, rc0, rc1, seg, gn, gr);

  float lsv[16], lbv[16];
  load16(ls, seg, lsv);
  load16(lb, seg, lbv);
  __syncthreads();

#pragma unroll
  for (int tt = 0; tt < 2; ++tt) {
    const int e0 = ebase + tt * 32;

    // E2: layer-1 MFMA from As, old-edge stash, NSR sum -> bf16 LDS
    f32x4 acc[2][4] = {};
    gemm_lds<2, 4, 8, 512>(W0p, L, As, w * 64, l, acc);

    bf16x8 old0[2], old1[2];
#pragma unroll
    for (int p = 0; p < 2; ++p) {
      const int row = p * 16 + tr;
      old0[p] = *(const bf16x8*)((const char*)As +
                                 ((row * 512 + seg * 16) ^ ((row & 7) << 4)));
      old1[p] = *(const bf16x8*)((const char*)As + ((row * 512 + 256 +
                                                     seg * 16) ^
                                                    ((row & 7) << 4)));
    }

#pragma unroll
    for (int p = 0; p < 2; ++p) {
      const int row = p * 16 + tr;
      float s[16];
#pragma unroll
      for (int k = 0; k < 8; ++k) {
        s[k] = bs2f(gn[p][0][k]) + bs2f(gr[p][0][k]);
        s[8 + k] = bs2f(gn[p][1][k]) + bs2f(gr[p][1][k]);
      }
      const int off0 = (row * 512 + seg * 16) ^ ((row & 7) << 4);
      const int off1 = (row * 512 + 256 + seg * 16) ^ ((row & 7) << 4);
      *(bf16x8*)((char*)nsrB + off0) = pack_bf16x8(s);
      *(bf16x8*)((char*)nsrB + off1) = pack_bf16x8(s + 8);
    }
    __syncthreads();

    // E3: h-build (acc + b0 + NSR, relu) -> h into As
#pragma unroll
    for (int ni = 0; ni < 4; ++ni) {
      const float bia = b0[w * 64 + ni * 16 + lm];
      const int col = w * 64 + ni * 16 + lm;
#pragma unroll
      for (int mi = 0; mi < 2; ++mi) {
        f32x4 v = acc[mi][ni];
#pragma unroll
        for (int i = 0; i < 4; ++i) {
          const int row = mi * 16 + g * 4 + i;
          const int noff = (row * 512 + col * 2) ^ ((row & 7) << 4);
          v[i] = fmaxf(
              v[i] + bia + bs2f(*(const short*)((const char*)nsrB + noff)),
              0.f);
        }
        store_tile(As, l, mi, w * 64 + ni * 16, v);
      }
    }
    __syncthreads();

    // E4+E5: layer 2 from As(h), y into nsrB
    f32x4 acc2[2][4] = {};
    gemm_lds<2, 4, 8, 512>(W1p, L, As, w * 64, l, acc2);
#pragma unroll
    for (int ni = 0; ni < 4; ++ni) {
      const float bia = b1[w * 64 + ni * 16 + lm];
#pragma unroll
      for (int mi = 0; mi < 2; ++mi) {
        f32x4 v = acc2[mi][ni];
#pragma unroll
        for (int i = 0; i < 4; ++i) v[i] += bia;
        store_tile(nsrB, l, mi, w * 64 + ni * 16, v);
      }
    }
    __syncthreads();  // all As reads done; all y writes visible

    // tail (tt==0): prep tile 1 — stage into As + indices + gathers,
    // all overlapped with this tile's epilogue below.
    if (tt == 0) {
      sn0 = senders[ebase + 32 + tr];
      rc0 = receivers[ebase + 32 + tr];
      sn1 = senders[ebase + 48 + tr];
      rc1 = receivers[ebase + 48 + tr];
      stage_tile256(edges_b + (size_t)(ebase + 32) * L, As, w, l);
      issue_gathers(NSb, NRb, sn0, sn1, rc0, rc1, seg, gn, gr);
    }

    // E6: LN + residual + vector stores (reads nsrB only)
#pragma unroll
    for (int p = 0; p < 2; ++p) {
      const int row = p * 16 + tr;
      float ne[16];
      ln_row(nsrB, row, seg, lsv, lbv, ne);
      const size_t e = (size_t)(e0 + row);
      *(bf16x8*)(new_e + e * L + seg * 8) = pack_bf16x8(ne);
      *(bf16x8*)(new_e + e * L + 128 + seg * 8) = pack_bf16x8(ne + 8);
      float r0[8], r1[8];
#pragma unroll
      for (int k = 0; k < 8; ++k) {
        r0[k] = bs2f(old0[p][k]) + ne[k];
        r1[k] = bs2f(old1[p][k]) + ne[8 + k];
      }
      *(bf16x8*)(edges_b + e * L + seg * 8) = pack_bf16x8(r0);
      *(bf16x8*)(edges_b + e * L + 128 + seg * 8) = pack_bf16x8(r1);
    }
    __syncthreads();  // nsrB free + next As staged (vmcnt drained here)
  }
}

// ---------------------------------------------------------------------------
// Node step (BM=16, fused aggregation + proj): X=[nodes_b | agg] where agg
// streams CONTIGUOUS new_e rows [start[n],start[n+1]) (CSR-ordered edges;
// same summation order as before -> bit-identical).
// ---------------------------------------------------------------------------
__global__ __launch_bounds__(256, 4) void node_step_mfma(
    float* __restrict__ nodes_f, short* __restrict__ nodes_b,
    const short* __restrict__ new_e, const int* __restrict__ start,
    const short* __restrict__ W0p, const float* __restrict__ b0,
    const short* __restrict__ W1p, const float* __restrict__ b1,
    const float* __restrict__ ls, const float* __restrict__ lb,
    const short* __restrict__ W0nS, const short* __restrict__ W0nR,
    short* __restrict__ NSb, short* __restrict__ NRb) {
  __shared__ char smem[16384];
  short* As = (short*)smem;            // [16][512] staging (16KB)
  short* hb = (short*)smem;            // h [16][256] overlays first 8KB
  short* yb = (short*)(smem + 8192);   // y second 8KB
  const int t = threadIdx.x, w = t >> 6, l = t & 63;
  const int lm = l & 15;
  const int tr = t >> 4, seg = t & 15;
  const int n0 = blockIdx.x * 16;

  // stage nodes half (async) ...
  stage_nodes_half16(nodes_b, As, w, l, n0);

  // ... while aggregating contiguous new_e rows into the agg half
  {
    const int grp = t >> 5, lc = t & 31;
#pragma unroll
    for (int i = 0; i < 2; ++i) {
      const int r = grp * 2 + i;
      const int n = n0 + r;
      const int b = start[n], e = start[n + 1];
      float acc[8] = {0.f, 0.f, 0.f, 0.f, 0.f, 0.f, 0.f, 0.f};
      for (int j = b; j < e; ++j) {
        const bf16x8 v = *(const bf16x8*)(new_e + (size_t)j * L + lc * 8);
#pragma unroll
        for (int k = 0; k < 8; ++k) acc[k] += bs2f(v[k]);
      }
      const int off = (r * 1024 + 512 + lc * 16) ^ ((r & 7) << 4);
      *(bf16x8*)((char*)As + off) = pack_bf16x8(acc);
    }
  }
  __syncthreads();

  f32x4 acc[1][4] = {};
  gemm_lds<1, 4, 16, 1024>(W0p, L, As, w * 64, l, acc);
  __syncthreads();

#pragma unroll
  for (int ni = 0; ni < 4; ++ni) {
    const float bia = b0[w * 64 + ni * 16 + lm];
    f32x4 v = acc[0][ni];
#pragma unroll
    for (int i = 0; i < 4; ++i) v[i] = fmaxf(v[i] + bia, 0.f);
    store_tile(hb, l, 0, w * 64 + ni * 16, v);
  }
  __syncthreads();

  f32x4 acc2[1][4] = {};
  gemm_lds<1, 4, 8, 512>(W1p, L, hb, w * 64, l, acc2);
  __syncthreads();
#pragma unroll
  for (int ni = 0; ni < 4; ++ni) {
    const float bia = b1[w * 64 + ni * 16 + lm];
    f32x4 v = acc2[0][ni];
#pragma unroll
    for (int i = 0; i < 4; ++i) v[i] += bia;
    store_tile(yb, l, 0, w * 64 + ni * 16, v);
  }
  __syncthreads();

  float lsv[16], lbv[16];
  load16(ls, seg, lsv);
  load16(lb, seg, lbv);
  {
    const int row = tr;  // 0..15
    float ne[16];
    ln_row(yb, row, seg, lsv, lbv, ne);
    const size_t n = (size_t)(n0 + row);
    float* nf = nodes_f + n * L;
    float fv[16];
    load16(nf, seg, fv);
    float nv[16];
#pragma unroll
    for (int k = 0; k < 16; ++k) nv[k] = fv[k] + ne[k];
    *(float4*)(nf + seg * 8) = make_float4(nv[0], nv[1], nv[2], nv[3]);
    *(float4*)(nf + seg * 8 + 4) = make_float4(nv[4], nv[5], nv[6], nv[7]);
    *(float4*)(nf + 128 + seg * 8) = make_float4(nv[8], nv[9], nv[10], nv[11]);
    *(float4*)(nf + 128 + seg * 8 + 4) = make_float4(nv[12], nv[13], nv[14], nv[15]);
    const bf16x8 nb0 = pack_bf16x8(nv);
    const bf16x8 nb1 = pack_bf16x8(nv + 8);
    *(bf16x8*)(nodes_b + n * L + seg * 8) = nb0;
    *(bf16x8*)(nodes_b + n * L + 128 + seg * 8) = nb1;
    // also place the new node row into hb (swizzled) for the fused proj
    const int off0 = (row * 512 + seg * 16) ^ ((row & 7) << 4);
    const int off1 = (row * 512 + 256 + seg * 16) ^ ((row & 7) << 4);
    *(bf16x8*)((char*)hb + off0) = nb0;
    *(bf16x8*)((char*)hb + off1) = nb1;
  }

  if (W0nS == nullptr) return;
  __syncthreads();

  // fused proj, sender panel
  {
    f32x4 pa[1][4] = {};
    gemm_lds<1, 4, 8, 512>(W0nS, L, hb, w * 64, l, pa);
#pragma unroll
    for (int ni = 0; ni < 4; ++ni)
      store_tile(yb, l, 0, w * 64 + ni * 16, pa[0][ni]);
    __syncthreads();
    {
      const int row = tr;
      const int off0 = (row * 512 + seg * 16) ^ ((row & 7) << 4);
      const int off1 = (row * 512 + 256 + seg * 16) ^ ((row & 7) << 4);
      *(bf16x8*)(NSb + (size_t)(n0 + row) * L + seg * 8) =
          *(const bf16x8*)((const char*)yb + off0);
      *(bf16x8*)(NSb + (size_t)(n0 + row) * L + 128 + seg * 8) =
          *(const bf16x8*)((const char*)yb + off1);
    }
  }
  __syncthreads();

  // fused proj, receiver panel
  {
    f32x4 pa[1][4] = {};
    gemm_lds<1, 4, 8, 512>(W0nR, L, hb, w * 64, l, pa);
#pragma unroll
    for (int ni = 0; ni < 4; ++ni)
      store_tile(yb, l, 0, w * 64 + ni * 16, pa[0][ni]);
    __syncthreads();
    {
      const int row = tr;
      const int off0 = (row * 512 + seg * 16) ^ ((row & 7) << 4);
      const int off1 = (row * 512 + 256 + seg * 16) ^ ((row & 7) << 4);
      *(bf16x8*)(NRb + (size_t)(n0 + row) * L + seg * 8) =
          *(const bf16x8*)((const char*)yb + off0);
      *(bf16x8*)(NRb + (size_t)(n0 + row) * L + 128 + seg * 8) =
          *(const bf16x8*)((const char*)yb + off1);
    }
  }
}

// ---------------------------------------------------------------------------
// Embedder: layer1 via zero-padded K=32 MFMA -> h in LDS -> MFMA layer2 ->
// LN -> dst. WF32: also write fp32 master. gidx: optional row gather
// (CSR-ordered edge features).
// ---------------------------------------------------------------------------
template <int K1, bool WF32>
__global__ __launch_bounds__(256) void embed_mfma(
    const float* __restrict__ x, const int* __restrict__ gidx,
    const short* __restrict__ W0p, const float* __restrict__ b0,
    const short* __restrict__ W1p, const float* __restrict__ b1,
    const float* __restrict__ ls, const float* __restrict__ lb,
    float* __restrict__ dst_f, short* __restrict__ dst_b) {
  __shared__ short hs[64 * 256];
  __shared__ short xsb[64 * 32];
  const int t = threadIdx.x, w = t >> 6, l = t & 63;
  const int lm = l & 15, g = l >> 4;
  const int tr = t >> 4, seg = t & 15;
  const int r0 = blockIdx.x * 64;

  if (t < 64) {
    const size_t srow = gidx ? (size_t)gidx[r0 + t] : (size_t)(r0 + t);
    const float* xr = x + srow * K1;
    float v[8] = {0.f, 0.f, 0.f, 0.f, 0.f, 0.f, 0.f, 0.f};
#pragma unroll
    for (int k = 0; k < K1; ++k) v[k] = xr[k];
    bf16x8 z;
#pragma unroll
    for (int k = 0; k < 8; ++k) z[k] = 0;
    char* rb = (char*)xsb + t * 64;
    *(bf16x8*)(rb + (0 ^ ((t & 3) << 4))) = pack_bf16x8(v);
#pragma unroll
    for (int gi = 1; gi < 4; ++gi) *(bf16x8*)(rb + ((gi * 16) ^ ((t & 3) << 4))) = z;
  }
  __syncthreads();

  f32x4 acc[4][4] = {};
  {
    bf16x8 a[4];
#pragma unroll
    for (int mi = 0; mi < 4; ++mi) {
      const int row = mi * 16 + lm;
      a[mi] = *(const bf16x8*)((const char*)xsb + row * 64 +
                               ((g * 16) ^ ((row & 3) << 4)));
    }
#pragma unroll
    for (int ni = 0; ni < 4; ++ni) {
      const int n = w * 64 + ni * 16 + lm;
      bf16x8 b = *(const bf16x8*)(W0p + n * 32 + g * 8);
#pragma unroll
      for (int mi = 0; mi < 4; ++mi)
        acc[mi][ni] =
            __builtin_amdgcn_mfma_f32_16x16x32_bf16(a[mi], b, acc[mi][ni], 0, 0, 0);
    }
  }
#pragma unroll
  for (int ni = 0; ni < 4; ++ni) {
    const float bia = b0[w * 64 + ni * 16 + lm];
#pragma unroll
    for (int mi = 0; mi < 4; ++mi) {
      f32x4 v = acc[mi][ni];
#pragma unroll
      for (int i = 0; i < 4; ++i) v[i] = fmaxf(v[i] + bia, 0.f);
      store_tile(hs, l, mi, w * 64 + ni * 16, v);
    }
  }
  __syncthreads();

  f32x4 acc2[4][4] = {};
  gemm_lds<4, 4, 8, 512>(W1p, L, hs, w * 64, l, acc2);
  __syncthreads();
#pragma unroll
  for (int ni = 0; ni < 4; ++ni) {
    const float bia = b1[w * 64 + ni * 16 + lm];
#pragma unroll
    for (int mi = 0; mi < 4; ++mi) {
      f32x4 v = acc2[mi][ni];
#pragma unroll
      for (int i = 0; i < 4; ++i) v[i] += bia;
      store_tile(hs, l, mi, w * 64 + ni * 16, v);
    }
  }
  __syncthreads();

  float lsv[16], lbv[16];
  load16(ls, seg, lsv);
  load16(lb, seg, lbv);
#pragma unroll
  for (int p = 0; p < 4; ++p) {
    const int row = p * 16 + tr;
    float ne[16];
    ln_row(hs, row, seg, lsv, lbv, ne);
    const size_t n = (size_t)(r0 + row);
    *(bf16x8*)(dst_b + n * L + seg * 8) = pack_bf16x8(ne);
    *(bf16x8*)(dst_b + n * L + 128 + seg * 8) = pack_bf16x8(ne + 8);
    if (WF32) {
      float* df = dst_f + n * L;
      *(float4*)(df + seg * 8) = make_float4(ne[0], ne[1], ne[2], ne[3]);
      *(float4*)(df + seg * 8 + 4) = make_float4(ne[4], ne[5], ne[6], ne[7]);
      *(float4*)(df + 128 + seg * 8) = make_float4(ne[8], ne[9], ne[10], ne[11]);
      *(float4*)(df + 128 + seg * 8 + 4) =
          make_float4(ne[12], ne[13], ne[14], ne[15]);
    }
  }
}

// ---------------------------------------------------------------------------
// Decoder: nodes_b (256 bf16) -> MFMA 256 relu -> MFMA 128 -> out (fp32)
// ---------------------------------------------------------------------------
__global__ __launch_bounds__(256) void decoder_mfma(
    const short* __restrict__ nodes_b, const short* __restrict__ W0p,
    const float* __restrict__ b0, const short* __restrict__ W1p,
    const float* __restrict__ b1, float* __restrict__ out) {
  __shared__ short hs[64 * 256];
  const int t = threadIdx.x, w = t >> 6, l = t & 63;
  const int lm = l & 15, g = l >> 4;
  const int n0 = blockIdx.x * 64;

  const short* baseA[4];
#pragma unroll
  for (int mi = 0; mi < 4; ++mi)
    baseA[mi] = nodes_b + (size_t)(n0 + mi * 16 + lm) * L;

  f32x4 acc[4][4] = {};
#pragma unroll
  for (int kc = 0; kc < 8; ++kc) {
    const int koff = kc * 32 + g * 8;
    bf16x8 a[4];
#pragma unroll
    for (int mi = 0; mi < 4; ++mi) a[mi] = *(const bf16x8*)(baseA[mi] + koff);
#pragma unroll
    for (int ni = 0; ni < 4; ++ni) {
      const int n = w * 64 + ni * 16 + lm;
      bf16x8 b = *(const bf16x8*)(W0p + ((size_t)kc * L + n) * 32 + g * 8);
#pragma unroll
      for (int mi = 0; mi < 4; ++mi)
        acc[mi][ni] = __builtin_amdgcn_mfma_f32_16x16x32_bf16(a[mi], b,
                                                             acc[mi][ni],
                                                             0, 0, 0);
    }
  }
#pragma unroll
  for (int ni = 0; ni < 4; ++ni) {
    const float bia = b0[w * 64 + ni * 16 + lm];
#pragma unroll
    for (int mi = 0; mi < 4; ++mi) {
      f32x4 v = acc[mi][ni];
#pragma unroll
      for (int i = 0; i < 4; ++i) v[i] = fmaxf(v[i] + bia, 0.f);
      store_tile(hs, l, mi, w * 64 + ni * 16, v);
    }
  }
  __syncthreads();

  f32x4 acc2[4][2] = {};
  gemm_lds<4, 2, 8, 512>(W1p, OUTD, hs, w * 32, l, acc2);

  float b14[2];
#pragma unroll
  for (int ni = 0; ni < 2; ++ni) b14[ni] = b1[w * 32 + ni * 16 + lm];
#pragma unroll
  for (int mi = 0; mi < 4; ++mi)
#pragma unroll
    for (int ni = 0; ni < 2; ++ni)
#pragma unroll
      for (int i = 0; i < 4; ++i) {
        const int row = n0 + mi * 16 + g * 4 + i;
        const int col = w * 32 + ni * 16 + lm;
        out[(size_t)row * OUTD + col] = acc2[mi][ni][i] + b14[ni];
      }
}

// ---------------------------------------------------------------------------
extern "C" void kernel_launch(void* const* d_in, const int* in_sizes, int n_in,
                              void* d_out, int out_size, void* d_ws,
                              size_t ws_size, hipStream_t stream) {
  const float* node_feats = (const float*)d_in[0];
  const float* edge_feats = (const float*)d_in[1];
  const int* senders = (const int*)d_in[2];
  const int* receivers = (const int*)d_in[3];
  auto f = [&](int i) { return (const float*)d_in[i]; };

  char* p = (char*)d_ws;
  auto alloc = [&](size_t bytes) {
    char* q = p;
    p += (bytes + 255) & ~(size_t)255;
    return q;
  };
  float* nodes_f = (float*)alloc((size_t)NN * L * 4);
  short* nodes_b = (short*)alloc((size_t)NN * L * 2);
  short* edges_b = (short*)alloc((size_t)NE * L * 2);
  short* new_e = (short*)alloc((size_t)NE * L * 2);
  short* NSb = (short*)alloc((size_t)NN * L * 2);
  short* NRb = (short*)alloc((size_t)NN * L * 2);
  int* deg = (int*)alloc((size_t)NN * 4);
  int* start = (int*)alloc((size_t)(NN + 16) * 4);
  int* cursor = (int*)alloc((size_t)NN * 4);
  int* elist = (int*)alloc((size_t)NE * 4);
  int* sn_p = (int*)alloc((size_t)NE * 4);
  int* rc_p = (int*)alloc((size_t)NE * 4);
  short* en_W0p = (short*)alloc(256 * 32 * 2);
  short* ee_W0p = (short*)alloc(256 * 32 * 2);
  short* en_W1p = (short*)alloc(65536 * 2);
  short* ee_W1p = (short*)alloc(65536 * 2);
  short* pe_W0p = (short*)alloc((size_t)4 * 768 * 256 * 2);
  short* pe_W1p = (short*)alloc((size_t)4 * 65536 * 2);
  short* pn_W0p = (short*)alloc((size_t)4 * 512 * 256 * 2);
  short* pn_W1p = (short*)alloc((size_t)4 * 65536 * 2);
  short* dn_W0p = (short*)alloc(65536 * 2);
  short* dn_W1p = (short*)alloc(32768 * 2);

  // CSR build; elist = stable (receiver, edge-id) order = edge permutation
  hipMemsetAsync(deg, 0, (size_t)NN * 4, stream);
  csr_hist<<<NE / 256, 256, 0, stream>>>(receivers, deg);
  csr_scan<<<1, 256, 0, stream>>>(deg, start, cursor);
  csr_scatter<<<NE / 256, 256, 0, stream>>>(receivers, cursor, elist);
  csr_sort<<<NN / 256, 256, 0, stream>>>(start, elist);
  permute_se<<<NE / 256, 256, 0, stream>>>(elist, senders, receivers, sn_p,
                                           rc_p);

  pack_w0_pad<<<32, 256, 0, stream>>>(f(4), en_W0p, 3);
  pack_w0_pad<<<32, 256, 0, stream>>>(f(10), ee_W0p, 4);
  pack_w<<<256, 256, 0, stream>>>(f(6), en_W1p, 256, 256, 1);
  pack_w<<<256, 256, 0, stream>>>(f(12), ee_W1p, 256, 256, 1);
  pack_w<<<1024, 256, 0, stream>>>(f(16), pe_W0p, 768, 256, 4);
  pack_w<<<512, 256, 0, stream>>>(f(18), pe_W1p, 256, 256, 4);
  pack_w<<<1024, 256, 0, stream>>>(f(22), pn_W0p, 512, 256, 4);
  pack_w<<<512, 256, 0, stream>>>(f(24), pn_W1p, 256, 256, 4);
  pack_w<<<256, 256, 0, stream>>>(f(28), dn_W0p, 256, 256, 1);
  pack_w<<<128, 256, 0, stream>>>(f(30), dn_W1p, 256, 128, 1);

  embed_mfma<3, true><<<NN / 64, 256, 0, stream>>>(
      node_feats, nullptr, en_W0p, f(5), en_W1p, f(7), f(8), f(9), nodes_f,
      nodes_b);
  // edge features gathered into CSR order
  embed_mfma<4, false><<<NE / 64, 256, 0, stream>>>(
      edge_feats, elist, ee_W0p, f(11), ee_W1p, f(13), f(14), f(15), nullptr,
      edges_b);

  for (int s = 0; s < SSTEPS; ++s) {
    const short* W0s = pe_W0p + (size_t)s * 768 * 256;
    if (s == 0)
      proj_mfma<<<dim3(NN / 32, 2), 256, 0, stream>>>(nodes_b, W0s, NSb, NRb);
    edge_step_mfma<<<NE / 64, 256, 0, stream>>>(
        NSb, NRb, edges_b, new_e, sn_p, rc_p, W0s, f(17) + (size_t)s * 256,
        pe_W1p + (size_t)s * 65536, f(19) + (size_t)s * 256,
        f(20) + (size_t)s * 256, f(21) + (size_t)s * 256);
    const short* W0n = (s + 1 < SSTEPS) ? pe_W0p + (size_t)(s + 1) * 768 * 256
                                        : nullptr;
    node_step_mfma<<<NN / 16, 256, 0, stream>>>(
        nodes_f, nodes_b, new_e, start, pn_W0p + (size_t)s * 512 * 256,
        f(23) + (size_t)s * 256, pn_W1p + (size_t)s * 65536,
        f(25) + (size_t)s * 256, f(26) + (size_t)s * 256,
        f(27) + (size_t)s * 256, W0n ? W0n + (size_t)8 * 256 * 32 : nullptr,
        W0n ? W0n + (size_t)16 * 256 * 32 : nullptr, NSb, NRb);
  }

  decoder_mfma<<<NN / 64, 256, 0, stream>>>(nodes_b, dn_W0p, f(29), dn_W1p,
                                            f(31), (float*)d_out);
}

// Round 17
// 805.384 us; speedup vs baseline: 2.2255x; 2.2255x over previous
//
#include <hip/hip_runtime.h>
#include <hip/hip_bf16.h>

#define NN 16384
#define NE 131072
#define L 256
#define SSTEPS 4
#define OUTD 128

typedef __attribute__((ext_vector_type(8))) short bf16x8;
typedef __attribute__((ext_vector_type(4))) float f32x4;

typedef const unsigned __attribute__((address_space(1)))* as1_u32p;
typedef unsigned __attribute__((address_space(3)))* as3_u32p;

__device__ __forceinline__ void gload16(const void* g, void* lds) {
  __builtin_amdgcn_global_load_lds((as1_u32p)g, (as3_u32p)lds, 16, 0, 0);
}

__device__ __forceinline__ short f2bs(float f) {
  unsigned u = __builtin_bit_cast(unsigned, f);
  u = (u + 0x7fffu + ((u >> 16) & 1u)) >> 16;
  return (short)u;
}
__device__ __forceinline__ float bs2f(short s) {
  unsigned u = ((unsigned)(unsigned short)s) << 16;
  return __builtin_bit_cast(float, u);
}
__device__ __forceinline__ unsigned cvt_pk_bf16(float lo, float hi) {
  unsigned r;
  asm("v_cvt_pk_bf16_f32 %0, %1, %2" : "=v"(r) : "v"(lo), "v"(hi));
  return r;
}
__device__ __forceinline__ bf16x8 pack_bf16x8(const float v[8]) {
  union { unsigned u[4]; bf16x8 b; } r;
#pragma unroll
  for (int k = 0; k < 4; ++k) r.u[k] = cvt_pk_bf16(v[2 * k], v[2 * k + 1]);
  return r.b;
}

// Store one 16x16 C-tile (f32x4 per lane) into swizzled bf16 LDS [R][256]
// (row stride 512B). byte ^= (row&7)<<4.
__device__ __forceinline__ void store_tile(short* hs, int l, int mi, int nb,
                                           f32x4 v) {
  const int lm = l & 15, g = l >> 4;
#pragma unroll
  for (int i = 0; i < 4; ++i) {
    const float part = __shfl_xor(v[i], 1);
    if ((l & 1) == 0) {
      const int row = mi * 16 + g * 4 + i;
      const int col = nb + lm;  // even
      const int off = (row * 512 + col * 2) ^ ((row & 7) << 4);
      *(unsigned*)((char*)hs + off) = cvt_pk_bf16(v[i], part);
    }
  }
}

// GEMM from swizzled bf16 LDS tile (row stride AST bytes) x packed W.
template <int MI, int NT, int KC, int AST>
__device__ __forceinline__ void gemm_lds(const short* __restrict__ Wp,
                                         int Ncols, const short* hs, int n0,
                                         int l, f32x4 acc[MI][NT]) {
  const int lm = l & 15, g = l >> 4;
#pragma unroll
  for (int kc = 0; kc < KC; ++kc) {
    bf16x8 a[MI];
#pragma unroll
    for (int mi = 0; mi < MI; ++mi) {
      const int row = mi * 16 + lm;
      const int off = (row * AST + kc * 64 + g * 16) ^ ((row & 7) << 4);
      a[mi] = *(const bf16x8*)((const char*)hs + off);
    }
#pragma unroll
    for (int ni = 0; ni < NT; ++ni) {
      const int n = n0 + ni * 16 + lm;
      bf16x8 b = *(const bf16x8*)(Wp + ((size_t)kc * Ncols + n) * 32 + g * 8);
#pragma unroll
      for (int mi = 0; mi < MI; ++mi)
        acc[mi][ni] =
            __builtin_amdgcn_mfma_f32_16x16x32_bf16(a[mi], b, acc[mi][ni], 0, 0, 0);
    }
  }
}

// Pack fp32 weight [K][N] (cnt stacked) into bf16 Wp[k/32][n][k%32].
__global__ void pack_w(const float* __restrict__ src, short* __restrict__ dst,
                       int K, int N, int cnt) {
  const size_t total = (size_t)K * N * cnt;
  for (size_t i = (size_t)blockIdx.x * blockDim.x + threadIdx.x; i < total;
       i += (size_t)gridDim.x * blockDim.x) {
    const size_t mat = i / ((size_t)K * N);
    const int rem = (int)(i - mat * (size_t)K * N);
    const int k = rem / N, n = rem - k * N;
    dst[mat * (size_t)K * N + ((size_t)(k >> 5) * N + n) * 32 + (k & 31)] =
        f2bs(src[i]);
  }
}

// Pack fp32 W0 [Kreal][256] into zero-padded bf16 [256][32] (K=32 fragment).
__global__ void pack_w0_pad(const float* __restrict__ src,
                            short* __restrict__ dst, int Kreal) {
  const int i = blockIdx.x * 256 + threadIdx.x;
  if (i >= 256 * 32) return;
  const int n = i >> 5, k = i & 31;
  dst[n * 32 + k] = (k < Kreal) ? f2bs(src[k * 256 + n]) : (short)0;
}

// ---------------------------------------------------------------------------
// Async staging: [32][256] bf16 tile (16KB) from 32 consecutive global rows.
// Source byte pre-XOR'd with (row&7)<<4; LDS linear (m173 both-sides rule).
// ---------------------------------------------------------------------------
__device__ __forceinline__ void stage_tile256(const short* __restrict__ src0,
                                              short* As, int w, int l) {
#pragma unroll
  for (int i = 0; i < 4; ++i) {
    const int rbase = w * 8 + i * 2;
    const int r = rbase + (l >> 5);
    const int boff = ((l & 31) * 16) ^ ((r & 7) << 4);
    gload16((const char*)(src0 + (size_t)r * L) + boff, As + rbase * 256);
  }
}

// BM=16 variant: stage cols 0..255 (bytes [0,512) of each 1024B row) of a
// [16][512] tile; lanes 0..31 active. Upper half produced in-kernel.
__device__ __forceinline__ void stage_nodes_half16(
    const short* __restrict__ a_src, short* As, int w, int l, int n0) {
#pragma unroll
  for (int i = 0; i < 4; ++i) {
    const int r = w * 4 + i;
    if (l < 32) {
      const int cb = (l * 16) ^ ((r & 7) << 4);
      gload16((const char*)(a_src + (size_t)(n0 + r) * L) + cb, As + r * 512);
    }
  }
}

// ---------------------------------------------------------------------------
// CSR build (deterministic: per-node lists sorted ascending by edge id).
// elist becomes the edge PERMUTATION: edge state lives in CSR order.
// ---------------------------------------------------------------------------
__global__ void csr_hist(const int* __restrict__ recv, int* __restrict__ deg) {
  const int e = blockIdx.x * 256 + threadIdx.x;
  atomicAdd(&deg[recv[e]], 1);
}
__global__ __launch_bounds__(256) void csr_scan(const int* __restrict__ deg,
                                                int* __restrict__ start,
                                                int* __restrict__ cursor) {
  __shared__ int part[256];
  const int t = threadIdx.x;
  int s = 0;
  for (int i = 0; i < NN / 256; ++i) s += deg[t * (NN / 256) + i];
  part[t] = s;
  __syncthreads();
  if (t == 0) {
    int acc = 0;
    for (int i = 0; i < 256; ++i) {
      const int v = part[i];
      part[i] = acc;
      acc += v;
    }
  }
  __syncthreads();
  int acc = part[t];
  for (int i = 0; i < NN / 256; ++i) {
    const int n = t * (NN / 256) + i;
    start[n] = acc;
    cursor[n] = acc;
    acc += deg[n];
  }
  if (t == 255) start[NN] = acc;
}
__global__ void csr_scatter(const int* __restrict__ recv,
                            int* __restrict__ cursor, int* __restrict__ elist) {
  const int e = blockIdx.x * 256 + threadIdx.x;
  const int p = atomicAdd(&cursor[recv[e]], 1);
  elist[p] = e;
}
__global__ void csr_sort(const int* __restrict__ start, int* __restrict__ elist) {
  const int n = blockIdx.x * blockDim.x + threadIdx.x;
  if (n >= NN) return;
  const int b = start[n], e = start[n + 1];
  for (int i = b + 1; i < e; ++i) {
    const int v = elist[i];
    int j = i - 1;
    while (j >= b && elist[j] > v) {
      elist[j + 1] = elist[j];
      --j;
    }
    elist[j + 1] = v;
  }
}
// permuted sender/receiver arrays: s/r of the edge at permuted position p
__global__ void permute_se(const int* __restrict__ elist,
                           const int* __restrict__ senders,
                           const int* __restrict__ receivers,
                           int* __restrict__ sn_p, int* __restrict__ rc_p) {
  const int p = blockIdx.x * 256 + threadIdx.x;
  const int e = elist[p];
  sn_p[p] = senders[e];
  rc_p[p] = receivers[e];
}

// ---------------------------------------------------------------------------
// Epilogue LN helpers
// ---------------------------------------------------------------------------
__device__ __forceinline__ void ln_row(const short* smem, int row, int seg,
                                       const float lsv[16], const float lbv[16],
                                       float ne[16]) {
  const int off0 = (row * 512 + seg * 16) ^ ((row & 7) << 4);
  const int off1 = (row * 512 + 256 + seg * 16) ^ ((row & 7) << 4);
  const bf16x8 y0 = *(const bf16x8*)((const char*)smem + off0);
  const bf16x8 y1 = *(const bf16x8*)((const char*)smem + off1);
  float v[16];
#pragma unroll
  for (int k = 0; k < 8; ++k) {
    v[k] = bs2f(y0[k]);
    v[8 + k] = bs2f(y1[k]);
  }
  float s = 0.f;
#pragma unroll
  for (int k = 0; k < 16; ++k) s += v[k];
#pragma unroll
  for (int o = 1; o < 16; o <<= 1) s += __shfl_xor(s, o);
  const float mu = s * (1.f / 256.f);
  float sq = 0.f;
#pragma unroll
  for (int k = 0; k < 16; ++k) {
    const float d = v[k] - mu;
    sq += d * d;
  }
#pragma unroll
  for (int o = 1; o < 16; o <<= 1) sq += __shfl_xor(sq, o);
  const float rstd = rsqrtf(sq * (1.f / 256.f) + 1e-6f);
#pragma unroll
  for (int k = 0; k < 16; ++k) ne[k] = (v[k] - mu) * rstd * lsv[k] + lbv[k];
}

__device__ __forceinline__ void load16(const float* __restrict__ p, int seg,
                                       float d[16]) {
  const float4 a0 = *(const float4*)(p + seg * 8);
  const float4 a1 = *(const float4*)(p + seg * 8 + 4);
  const float4 a2 = *(const float4*)(p + 128 + seg * 8);
  const float4 a3 = *(const float4*)(p + 128 + seg * 8 + 4);
  d[0] = a0.x; d[1] = a0.y; d[2] = a0.z; d[3] = a0.w;
  d[4] = a1.x; d[5] = a1.y; d[6] = a1.z; d[7] = a1.w;
  d[8] = a2.x; d[9] = a2.y; d[10] = a2.z; d[11] = a2.w;
  d[12] = a3.x; d[13] = a3.y; d[14] = a3.z; d[15] = a3.w;
}

// ---------------------------------------------------------------------------
// Projection (step 0 only): P = nodes_b @ W0_panel (K=256) -> bf16 [NN][256].
// blockIdx.y: 0 -> sender panel, 1 -> receiver panel.
// ---------------------------------------------------------------------------
__global__ __launch_bounds__(256, 4) void proj_mfma(
    const short* __restrict__ nodes_b, const short* __restrict__ Wfull,
    short* __restrict__ NSb, short* __restrict__ NRb) {
  __shared__ char smem[16384];
  short* As = (short*)smem;
  const int t = threadIdx.x, w = t >> 6, l = t & 63;
  const int tr = t >> 4, seg = t & 15;
  const int n0 = blockIdx.x * 32;
  const short* Wp = Wfull + (size_t)(8 + blockIdx.y * 8) * 256 * 32;
  short* out = blockIdx.y ? NRb : NSb;

  stage_tile256(nodes_b + (size_t)n0 * L, As, w, l);
  __syncthreads();

  f32x4 acc[2][4] = {};
  gemm_lds<2, 4, 8, 512>(Wp, L, As, w * 64, l, acc);
  __syncthreads();
#pragma unroll
  for (int ni = 0; ni < 4; ++ni)
#pragma unroll
    for (int mi = 0; mi < 2; ++mi)
      store_tile(As, l, mi, w * 64 + ni * 16, acc[mi][ni]);
  __syncthreads();

#pragma unroll
  for (int p = 0; p < 2; ++p) {
    const int row = p * 16 + tr;
    const int off0 = (row * 512 + seg * 16) ^ ((row & 7) << 4);
    const int off1 = (row * 512 + 256 + seg * 16) ^ ((row & 7) << 4);
    *(bf16x8*)(out + (size_t)(n0 + row) * L + seg * 8) =
        *(const bf16x8*)((const char*)As + off0);
    *(bf16x8*)(out + (size_t)(n0 + row) * L + 128 + seg * 8) =
        *(const bf16x8*)((const char*)As + off1);
  }
}

// ---------------------------------------------------------------------------
// Edge step (CSR-ordered edges): h = relu(edges@W0_e + NS[snd] + NR[rcv] +
// b0); y = h@W1 + b1; LN -> edges_b += ne (old stashed from LDS); new_e = ne.
// Receivers are non-decreasing -> NR gathers are L1/L2-local.  32KB LDS.
// launch_bounds (256,4): (256,5) squeezed VGPR to 48 and broke the early
// NS/NR gather overlap (r12); two-tile pipelining spilled to scratch (r16).
// ---------------------------------------------------------------------------
__global__ __launch_bounds__(256, 4) void edge_step_mfma(
    const short* __restrict__ NSb, const short* __restrict__ NRb,
    short* __restrict__ edges_b, short* __restrict__ new_e,
    const int* __restrict__ senders, const int* __restrict__ receivers,
    const short* __restrict__ W0p, const float* __restrict__ b0,
    const short* __restrict__ W1p, const float* __restrict__ b1,
    const float* __restrict__ ls, const float* __restrict__ lb) {
  __shared__ char smem[32768];
  short* As = (short*)smem;               // [32][256] staged edges; later h
  short* nsrB = (short*)(smem + 16384);   // [32][256] bf16 NS+NR; later y
  const int t = threadIdx.x, w = t >> 6, l = t & 63;
  const int lm = l & 15, g = l >> 4;
  const int tr = t >> 4, seg = t & 15;
  const int e0 = blockIdx.x * 32;

  // E1: indices + self-row staging
  const int sn0 = senders[e0 + tr], rc0 = receivers[e0 + tr];
  const int sn1 = senders[e0 + 16 + tr], rc1 = receivers[e0 + 16 + tr];
  stage_tile256(edges_b + (size_t)e0 * L, As, w, l);
  __syncthreads();

  // E2: NSR gathers (issued first), layer-1 MFMA, old-edge stash,
  //     NSR sum -> bf16 LDS
  bf16x8 gn[2][2], gr[2][2];
  {
    const short* p0 = NSb + (size_t)sn0 * L + seg * 8;
    gn[0][0] = *(const bf16x8*)p0;
    gn[0][1] = *(const bf16x8*)(p0 + 128);
    const short* p1 = NSb + (size_t)sn1 * L + seg * 8;
    gn[1][0] = *(const bf16x8*)p1;
    gn[1][1] = *(const bf16x8*)(p1 + 128);
    const short* q0 = NRb + (size_t)rc0 * L + seg * 8;
    gr[0][0] = *(const bf16x8*)q0;
    gr[0][1] = *(const bf16x8*)(q0 + 128);
    const short* q1 = NRb + (size_t)rc1 * L + seg * 8;
    gr[1][0] = *(const bf16x8*)q1;
    gr[1][1] = *(const bf16x8*)(q1 + 128);
  }

  f32x4 acc[2][4] = {};
  gemm_lds<2, 4, 8, 512>(W0p, L, As, w * 64, l, acc);

  bf16x8 old0[2], old1[2];
#pragma unroll
  for (int p = 0; p < 2; ++p) {
    const int row = p * 16 + tr;
    old0[p] = *(const bf16x8*)((const char*)As +
                               ((row * 512 + seg * 16) ^ ((row & 7) << 4)));
    old1[p] = *(const bf16x8*)((const char*)As +
                               ((row * 512 + 256 + seg * 16) ^ ((row & 7) << 4)));
  }

#pragma unroll
  for (int p = 0; p < 2; ++p) {
    const int row = p * 16 + tr;
    float s[16];
#pragma unroll
    for (int k = 0; k < 8; ++k) {
      s[k] = bs2f(gn[p][0][k]) + bs2f(gr[p][0][k]);
      s[8 + k] = bs2f(gn[p][1][k]) + bs2f(gr[p][1][k]);
    }
    const int off0 = (row * 512 + seg * 16) ^ ((row & 7) << 4);
    const int off1 = (row * 512 + 256 + seg * 16) ^ ((row & 7) << 4);
    *(bf16x8*)((char*)nsrB + off0) = pack_bf16x8(s);
    *(bf16x8*)((char*)nsrB + off1) = pack_bf16x8(s + 8);
  }
  __syncthreads();

  // E3: h-build (acc + b0 + NSR, relu) -> h into As
#pragma unroll
  for (int ni = 0; ni < 4; ++ni) {
    const float bia = b0[w * 64 + ni * 16 + lm];
    const int col = w * 64 + ni * 16 + lm;
#pragma unroll
    for (int mi = 0; mi < 2; ++mi) {
      f32x4 v = acc[mi][ni];
#pragma unroll
      for (int i = 0; i < 4; ++i) {
        const int row = mi * 16 + g * 4 + i;
        const int noff = (row * 512 + col * 2) ^ ((row & 7) << 4);
        v[i] = fmaxf(v[i] + bia + bs2f(*(const short*)((const char*)nsrB + noff)),
                     0.f);
      }
      store_tile(As, l, mi, w * 64 + ni * 16, v);
    }
  }
  __syncthreads();

  // E4+E5: layer 2, y into nsrB region (nsr consumed at E3)
  f32x4 acc2[2][4] = {};
  gemm_lds<2, 4, 8, 512>(W1p, L, As, w * 64, l, acc2);
#pragma unroll
  for (int ni = 0; ni < 4; ++ni) {
    const float bia = b1[w * 64 + ni * 16 + lm];
#pragma unroll
    for (int mi = 0; mi < 2; ++mi) {
      f32x4 v = acc2[mi][ni];
#pragma unroll
      for (int i = 0; i < 4; ++i) v[i] += bia;
      store_tile(nsrB, l, mi, w * 64 + ni * 16, v);
    }
  }
  __syncthreads();

  // E6: LN + residual + vector stores
  float lsv[16], lbv[16];
  load16(ls, seg, lsv);
  load16(lb, seg, lbv);
#pragma unroll
  for (int p = 0; p < 2; ++p) {
    const int row = p * 16 + tr;
    float ne[16];
    ln_row(nsrB, row, seg, lsv, lbv, ne);
    const size_t e = (size_t)(e0 + row);
    *(bf16x8*)(new_e + e * L + seg * 8) = pack_bf16x8(ne);
    *(bf16x8*)(new_e + e * L + 128 + seg * 8) = pack_bf16x8(ne + 8);
    float r0[8], r1[8];
#pragma unroll
    for (int k = 0; k < 8; ++k) {
      r0[k] = bs2f(old0[p][k]) + ne[k];
      r1[k] = bs2f(old1[p][k]) + ne[8 + k];
    }
    *(bf16x8*)(edges_b + e * L + seg * 8) = pack_bf16x8(r0);
    *(bf16x8*)(edges_b + e * L + 128 + seg * 8) = pack_bf16x8(r1);
  }
}

// ---------------------------------------------------------------------------
// Node step (BM=16, fused aggregation + proj): X=[nodes_b | agg] where agg
// streams CONTIGUOUS new_e rows [start[n],start[n+1]) (CSR-ordered edges;
// same summation order as before -> bit-identical).
// ---------------------------------------------------------------------------
__global__ __launch_bounds__(256, 4) void node_step_mfma(
    float* __restrict__ nodes_f, short* __restrict__ nodes_b,
    const short* __restrict__ new_e, const int* __restrict__ start,
    const short* __restrict__ W0p, const float* __restrict__ b0,
    const short* __restrict__ W1p, const float* __restrict__ b1,
    const float* __restrict__ ls, const float* __restrict__ lb,
    const short* __restrict__ W0nS, const short* __restrict__ W0nR,
    short* __restrict__ NSb, short* __restrict__ NRb) {
  __shared__ char smem[16384];
  short* As = (short*)smem;            // [16][512] staging (16KB)
  short* hb = (short*)smem;            // h [16][256] overlays first 8KB
  short* yb = (short*)(smem + 8192);   // y second 8KB
  const int t = threadIdx.x, w = t >> 6, l = t & 63;
  const int lm = l & 15;
  const int tr = t >> 4, seg = t & 15;
  const int n0 = blockIdx.x * 16;

  // stage nodes half (async) ...
  stage_nodes_half16(nodes_b, As, w, l, n0);

  // ... while aggregating contiguous new_e rows into the agg half
  {
    const int grp = t >> 5, lc = t & 31;
#pragma unroll
    for (int i = 0; i < 2; ++i) {
      const int r = grp * 2 + i;
      const int n = n0 + r;
      const int b = start[n], e = start[n + 1];
      float acc[8] = {0.f, 0.f, 0.f, 0.f, 0.f, 0.f, 0.f, 0.f};
      for (int j = b; j < e; ++j) {
        const bf16x8 v = *(const bf16x8*)(new_e + (size_t)j * L + lc * 8);
#pragma unroll
        for (int k = 0; k < 8; ++k) acc[k] += bs2f(v[k]);
      }
      const int off = (r * 1024 + 512 + lc * 16) ^ ((r & 7) << 4);
      *(bf16x8*)((char*)As + off) = pack_bf16x8(acc);
    }
  }
  __syncthreads();

  f32x4 acc[1][4] = {};
  gemm_lds<1, 4, 16, 1024>(W0p, L, As, w * 64, l, acc);
  __syncthreads();

#pragma unroll
  for (int ni = 0; ni < 4; ++ni) {
    const float bia = b0[w * 64 + ni * 16 + lm];
    f32x4 v = acc[0][ni];
#pragma unroll
    for (int i = 0; i < 4; ++i) v[i] = fmaxf(v[i] + bia, 0.f);
    store_tile(hb, l, 0, w * 64 + ni * 16, v);
  }
  __syncthreads();

  f32x4 acc2[1][4] = {};
  gemm_lds<1, 4, 8, 512>(W1p, L, hb, w * 64, l, acc2);
  __syncthreads();
#pragma unroll
  for (int ni = 0; ni < 4; ++ni) {
    const float bia = b1[w * 64 + ni * 16 + lm];
    f32x4 v = acc2[0][ni];
#pragma unroll
    for (int i = 0; i < 4; ++i) v[i] += bia;
    store_tile(yb, l, 0, w * 64 + ni * 16, v);
  }
  __syncthreads();

  float lsv[16], lbv[16];
  load16(ls, seg, lsv);
  load16(lb, seg, lbv);
  {
    const int row = tr;  // 0..15
    float ne[16];
    ln_row(yb, row, seg, lsv, lbv, ne);
    const size_t n = (size_t)(n0 + row);
    float* nf = nodes_f + n * L;
    float fv[16];
    load16(nf, seg, fv);
    float nv[16];
#pragma unroll
    for (int k = 0; k < 16; ++k) nv[k] = fv[k] + ne[k];
    *(float4*)(nf + seg * 8) = make_float4(nv[0], nv[1], nv[2], nv[3]);
    *(float4*)(nf + seg * 8 + 4) = make_float4(nv[4], nv[5], nv[6], nv[7]);
    *(float4*)(nf + 128 + seg * 8) = make_float4(nv[8], nv[9], nv[10], nv[11]);
    *(float4*)(nf + 128 + seg * 8 + 4) = make_float4(nv[12], nv[13], nv[14], nv[15]);
    const bf16x8 nb0 = pack_bf16x8(nv);
    const bf16x8 nb1 = pack_bf16x8(nv + 8);
    *(bf16x8*)(nodes_b + n * L + seg * 8) = nb0;
    *(bf16x8*)(nodes_b + n * L + 128 + seg * 8) = nb1;
    // also place the new node row into hb (swizzled) for the fused proj
    const int off0 = (row * 512 + seg * 16) ^ ((row & 7) << 4);
    const int off1 = (row * 512 + 256 + seg * 16) ^ ((row & 7) << 4);
    *(bf16x8*)((char*)hb + off0) = nb0;
    *(bf16x8*)((char*)hb + off1) = nb1;
  }

  if (W0nS == nullptr) return;
  __syncthreads();

  // fused proj, sender panel
  {
    f32x4 pa[1][4] = {};
    gemm_lds<1, 4, 8, 512>(W0nS, L, hb, w * 64, l, pa);
#pragma unroll
    for (int ni = 0; ni < 4; ++ni)
      store_tile(yb, l, 0, w * 64 + ni * 16, pa[0][ni]);
    __syncthreads();
    {
      const int row = tr;
      const int off0 = (row * 512 + seg * 16) ^ ((row & 7) << 4);
      const int off1 = (row * 512 + 256 + seg * 16) ^ ((row & 7) << 4);
      *(bf16x8*)(NSb + (size_t)(n0 + row) * L + seg * 8) =
          *(const bf16x8*)((const char*)yb + off0);
      *(bf16x8*)(NSb + (size_t)(n0 + row) * L + 128 + seg * 8) =
          *(const bf16x8*)((const char*)yb + off1);
    }
  }
  __syncthreads();

  // fused proj, receiver panel
  {
    f32x4 pa[1][4] = {};
    gemm_lds<1, 4, 8, 512>(W0nR, L, hb, w * 64, l, pa);
#pragma unroll
    for (int ni = 0; ni < 4; ++ni)
      store_tile(yb, l, 0, w * 64 + ni * 16, pa[0][ni]);
    __syncthreads();
    {
      const int row = tr;
      const int off0 = (row * 512 + seg * 16) ^ ((row & 7) << 4);
      const int off1 = (row * 512 + 256 + seg * 16) ^ ((row & 7) << 4);
      *(bf16x8*)(NRb + (size_t)(n0 + row) * L + seg * 8) =
          *(const bf16x8*)((const char*)yb + off0);
      *(bf16x8*)(NRb + (size_t)(n0 + row) * L + 128 + seg * 8) =
          *(const bf16x8*)((const char*)yb + off1);
    }
  }
}

// ---------------------------------------------------------------------------
// Embedder: layer1 via zero-padded K=32 MFMA -> h in LDS -> MFMA layer2 ->
// LN -> dst. WF32: also write fp32 master. gidx: optional row gather
// (CSR-ordered edge features).
// ---------------------------------------------------------------------------
template <int K1, bool WF32>
__global__ __launch_bounds__(256) void embed_mfma(
    const float* __restrict__ x, const int* __restrict__ gidx,
    const short* __restrict__ W0p, const float* __restrict__ b0,
    const short* __restrict__ W1p, const float* __restrict__ b1,
    const float* __restrict__ ls, const float* __restrict__ lb,
    float* __restrict__ dst_f, short* __restrict__ dst_b) {
  __shared__ short hs[64 * 256];
  __shared__ short xsb[64 * 32];
  const int t = threadIdx.x, w = t >> 6, l = t & 63;
  const int lm = l & 15, g = l >> 4;
  const int tr = t >> 4, seg = t & 15;
  const int r0 = blockIdx.x * 64;

  if (t < 64) {
    const size_t srow = gidx ? (size_t)gidx[r0 + t] : (size_t)(r0 + t);
    const float* xr = x + srow * K1;
    float v[8] = {0.f, 0.f, 0.f, 0.f, 0.f, 0.f, 0.f, 0.f};
#pragma unroll
    for (int k = 0; k < K1; ++k) v[k] = xr[k];
    bf16x8 z;
#pragma unroll
    for (int k = 0; k < 8; ++k) z[k] = 0;
    char* rb = (char*)xsb + t * 64;
    *(bf16x8*)(rb + (0 ^ ((t & 3) << 4))) = pack_bf16x8(v);
#pragma unroll
    for (int gi = 1; gi < 4; ++gi) *(bf16x8*)(rb + ((gi * 16) ^ ((t & 3) << 4))) = z;
  }
  __syncthreads();

  f32x4 acc[4][4] = {};
  {
    bf16x8 a[4];
#pragma unroll
    for (int mi = 0; mi < 4; ++mi) {
      const int row = mi * 16 + lm;
      a[mi] = *(const bf16x8*)((const char*)xsb + row * 64 +
                               ((g * 16) ^ ((row & 3) << 4)));
    }
#pragma unroll
    for (int ni = 0; ni < 4; ++ni) {
      const int n = w * 64 + ni * 16 + lm;
      bf16x8 b = *(const bf16x8*)(W0p + n * 32 + g * 8);
#pragma unroll
      for (int mi = 0; mi < 4; ++mi)
        acc[mi][ni] =
            __builtin_amdgcn_mfma_f32_16x16x32_bf16(a[mi], b, acc[mi][ni], 0, 0, 0);
    }
  }
#pragma unroll
  for (int ni = 0; ni < 4; ++ni) {
    const float bia = b0[w * 64 + ni * 16 + lm];
#pragma unroll
    for (int mi = 0; mi < 4; ++mi) {
      f32x4 v = acc[mi][ni];
#pragma unroll
      for (int i = 0; i < 4; ++i) v[i] = fmaxf(v[i] + bia, 0.f);
      store_tile(hs, l, mi, w * 64 + ni * 16, v);
    }
  }
  __syncthreads();

  f32x4 acc2[4][4] = {};
  gemm_lds<4, 4, 8, 512>(W1p, L, hs, w * 64, l, acc2);
  __syncthreads();
#pragma unroll
  for (int ni = 0; ni < 4; ++ni) {
    const float bia = b1[w * 64 + ni * 16 + lm];
#pragma unroll
    for (int mi = 0; mi < 4; ++mi) {
      f32x4 v = acc2[mi][ni];
#pragma unroll
      for (int i = 0; i < 4; ++i) v[i] += bia;
      store_tile(hs, l, mi, w * 64 + ni * 16, v);
    }
  }
  __syncthreads();

  float lsv[16], lbv[16];
  load16(ls, seg, lsv);
  load16(lb, seg, lbv);
#pragma unroll
  for (int p = 0; p < 4; ++p) {
    const int row = p * 16 + tr;
    float ne[16];
    ln_row(hs, row, seg, lsv, lbv, ne);
    const size_t n = (size_t)(r0 + row);
    *(bf16x8*)(dst_b + n * L + seg * 8) = pack_bf16x8(ne);
    *(bf16x8*)(dst_b + n * L + 128 + seg * 8) = pack_bf16x8(ne + 8);
    if (WF32) {
      float* df = dst_f + n * L;
      *(float4*)(df + seg * 8) = make_float4(ne[0], ne[1], ne[2], ne[3]);
      *(float4*)(df + seg * 8 + 4) = make_float4(ne[4], ne[5], ne[6], ne[7]);
      *(float4*)(df + 128 + seg * 8) = make_float4(ne[8], ne[9], ne[10], ne[11]);
      *(float4*)(df + 128 + seg * 8 + 4) =
          make_float4(ne[12], ne[13], ne[14], ne[15]);
    }
  }
}

// ---------------------------------------------------------------------------
// Decoder: nodes_b (256 bf16) -> MFMA 256 relu -> MFMA 128 -> out (fp32)
// ---------------------------------------------------------------------------
__global__ __launch_bounds__(256) void decoder_mfma(
    const short* __restrict__ nodes_b, const short* __restrict__ W0p,
    const float* __restrict__ b0, const short* __restrict__ W1p,
    const float* __restrict__ b1, float* __restrict__ out) {
  __shared__ short hs[64 * 256];
  const int t = threadIdx.x, w = t >> 6, l = t & 63;
  const int lm = l & 15, g = l >> 4;
  const int n0 = blockIdx.x * 64;

  const short* baseA[4];
#pragma unroll
  for (int mi = 0; mi < 4; ++mi)
    baseA[mi] = nodes_b + (size_t)(n0 + mi * 16 + lm) * L;

  f32x4 acc[4][4] = {};
#pragma unroll
  for (int kc = 0; kc < 8; ++kc) {
    const int koff = kc * 32 + g * 8;
    bf16x8 a[4];
#pragma unroll
    for (int mi = 0; mi < 4; ++mi) a[mi] = *(const bf16x8*)(baseA[mi] + koff);
#pragma unroll
    for (int ni = 0; ni < 4; ++ni) {
      const int n = w * 64 + ni * 16 + lm;
      bf16x8 b = *(const bf16x8*)(W0p + ((size_t)kc * L + n) * 32 + g * 8);
#pragma unroll
      for (int mi = 0; mi < 4; ++mi)
        acc[mi][ni] = __builtin_amdgcn_mfma_f32_16x16x32_bf16(a[mi], b,
                                                             acc[mi][ni],
                                                             0, 0, 0);
    }
  }
#pragma unroll
  for (int ni = 0; ni < 4; ++ni) {
    const float bia = b0[w * 64 + ni * 16 + lm];
#pragma unroll
    for (int mi = 0; mi < 4; ++mi) {
      f32x4 v = acc[mi][ni];
#pragma unroll
      for (int i = 0; i < 4; ++i) v[i] = fmaxf(v[i] + bia, 0.f);
      store_tile(hs, l, mi, w * 64 + ni * 16, v);
    }
  }
  __syncthreads();

  f32x4 acc2[4][2] = {};
  gemm_lds<4, 2, 8, 512>(W1p, OUTD, hs, w * 32, l, acc2);

  float b14[2];
#pragma unroll
  for (int ni = 0; ni < 2; ++ni) b14[ni] = b1[w * 32 + ni * 16 + lm];
#pragma unroll
  for (int mi = 0; mi < 4; ++mi)
#pragma unroll
    for (int ni = 0; ni < 2; ++ni)
#pragma unroll
      for (int i = 0; i < 4; ++i) {
        const int row = n0 + mi * 16 + g * 4 + i;
        const int col = w * 32 + ni * 16 + lm;
        out[(size_t)row * OUTD + col] = acc2[mi][ni][i] + b14[ni];
      }
}

// ---------------------------------------------------------------------------
extern "C" void kernel_launch(void* const* d_in, const int* in_sizes, int n_in,
                              void* d_out, int out_size, void* d_ws,
                              size_t ws_size, hipStream_t stream) {
  const float* node_feats = (const float*)d_in[0];
  const float* edge_feats = (const float*)d_in[1];
  const int* senders = (const int*)d_in[2];
  const int* receivers = (const int*)d_in[3];
  auto f = [&](int i) { return (const float*)d_in[i]; };

  char* p = (char*)d_ws;
  auto alloc = [&](size_t bytes) {
    char* q = p;
    p += (bytes + 255) & ~(size_t)255;
    return q;
  };
  float* nodes_f = (float*)alloc((size_t)NN * L * 4);
  short* nodes_b = (short*)alloc((size_t)NN * L * 2);
  short* edges_b = (short*)alloc((size_t)NE * L * 2);
  short* new_e = (short*)alloc((size_t)NE * L * 2);
  short* NSb = (short*)alloc((size_t)NN * L * 2);
  short* NRb = (short*)alloc((size_t)NN * L * 2);
  int* deg = (int*)alloc((size_t)NN * 4);
  int* start = (int*)alloc((size_t)(NN + 16) * 4);
  int* cursor = (int*)alloc((size_t)NN * 4);
  int* elist = (int*)alloc((size_t)NE * 4);
  int* sn_p = (int*)alloc((size_t)NE * 4);
  int* rc_p = (int*)alloc((size_t)NE * 4);
  short* en_W0p = (short*)alloc(256 * 32 * 2);
  short* ee_W0p = (short*)alloc(256 * 32 * 2);
  short* en_W1p = (short*)alloc(65536 * 2);
  short* ee_W1p = (short*)alloc(65536 * 2);
  short* pe_W0p = (short*)alloc((size_t)4 * 768 * 256 * 2);
  short* pe_W1p = (short*)alloc((size_t)4 * 65536 * 2);
  short* pn_W0p = (short*)alloc((size_t)4 * 512 * 256 * 2);
  short* pn_W1p = (short*)alloc((size_t)4 * 65536 * 2);
  short* dn_W0p = (short*)alloc(65536 * 2);
  short* dn_W1p = (short*)alloc(32768 * 2);

  // CSR build; elist = stable (receiver, edge-id) order = edge permutation
  hipMemsetAsync(deg, 0, (size_t)NN * 4, stream);
  csr_hist<<<NE / 256, 256, 0, stream>>>(receivers, deg);
  csr_scan<<<1, 256, 0, stream>>>(deg, start, cursor);
  csr_scatter<<<NE / 256, 256, 0, stream>>>(receivers, cursor, elist);
  csr_sort<<<NN / 256, 256, 0, stream>>>(start, elist);
  permute_se<<<NE / 256, 256, 0, stream>>>(elist, senders, receivers, sn_p,
                                           rc_p);

  pack_w0_pad<<<32, 256, 0, stream>>>(f(4), en_W0p, 3);
  pack_w0_pad<<<32, 256, 0, stream>>>(f(10), ee_W0p, 4);
  pack_w<<<256, 256, 0, stream>>>(f(6), en_W1p, 256, 256, 1);
  pack_w<<<256, 256, 0, stream>>>(f(12), ee_W1p, 256, 256, 1);
  pack_w<<<1024, 256, 0, stream>>>(f(16), pe_W0p, 768, 256, 4);
  pack_w<<<512, 256, 0, stream>>>(f(18), pe_W1p, 256, 256, 4);
  pack_w<<<1024, 256, 0, stream>>>(f(22), pn_W0p, 512, 256, 4);
  pack_w<<<512, 256, 0, stream>>>(f(24), pn_W1p, 256, 256, 4);
  pack_w<<<256, 256, 0, stream>>>(f(28), dn_W0p, 256, 256, 1);
  pack_w<<<128, 256, 0, stream>>>(f(30), dn_W1p, 256, 128, 1);

  embed_mfma<3, true><<<NN / 64, 256, 0, stream>>>(
      node_feats, nullptr, en_W0p, f(5), en_W1p, f(7), f(8), f(9), nodes_f,
      nodes_b);
  // edge features gathered into CSR order
  embed_mfma<4, false><<<NE / 64, 256, 0, stream>>>(
      edge_feats, elist, ee_W0p, f(11), ee_W1p, f(13), f(14), f(15), nullptr,
      edges_b);

  for (int s = 0; s < SSTEPS; ++s) {
    const short* W0s = pe_W0p + (size_t)s * 768 * 256;
    if (s == 0)
      proj_mfma<<<dim3(NN / 32, 2), 256, 0, stream>>>(nodes_b, W0s, NSb, NRb);
    edge_step_mfma<<<NE / 32, 256, 0, stream>>>(
        NSb, NRb, edges_b, new_e, sn_p, rc_p, W0s, f(17) + (size_t)s * 256,
        pe_W1p + (size_t)s * 65536, f(19) + (size_t)s * 256,
        f(20) + (size_t)s * 256, f(21) + (size_t)s * 256);
    const short* W0n = (s + 1 < SSTEPS) ? pe_W0p + (size_t)(s + 1) * 768 * 256
                                        : nullptr;
    node_step_mfma<<<NN / 16, 256, 0, stream>>>(
        nodes_f, nodes_b, new_e, start, pn_W0p + (size_t)s * 512 * 256,
        f(23) + (size_t)s * 256, pn_W1p + (size_t)s * 65536,
        f(25) + (size_t)s * 256, f(26) + (size_t)s * 256,
        f(27) + (size_t)s * 256, W0n ? W0n + (size_t)8 * 256 * 32 : nullptr,
        W0n ? W0n + (size_t)16 * 256 * 32 : nullptr, NSb, NRb);
  }

  decoder_mfma<<<NN / 64, 256, 0, stream>>>(nodes_b, dn_W0p, f(29), dn_W1p,
                                            f(31), (float*)d_out);
}

// Round 18
// 799.755 us; speedup vs baseline: 2.2412x; 1.0070x over previous
//
#include <hip/hip_runtime.h>
#include <hip/hip_bf16.h>

#define NN 16384
#define NE 131072
#define L 256
#define SSTEPS 4
#define OUTD 128

typedef __attribute__((ext_vector_type(8))) short bf16x8;
typedef __attribute__((ext_vector_type(4))) float f32x4;

typedef const unsigned __attribute__((address_space(1)))* as1_u32p;
typedef unsigned __attribute__((address_space(3)))* as3_u32p;

__device__ __forceinline__ void gload16(const void* g, void* lds) {
  __builtin_amdgcn_global_load_lds((as1_u32p)g, (as3_u32p)lds, 16, 0, 0);
}

__device__ __forceinline__ short f2bs(float f) {
  unsigned u = __builtin_bit_cast(unsigned, f);
  u = (u + 0x7fffu + ((u >> 16) & 1u)) >> 16;
  return (short)u;
}
__device__ __forceinline__ float bs2f(short s) {
  unsigned u = ((unsigned)(unsigned short)s) << 16;
  return __builtin_bit_cast(float, u);
}
__device__ __forceinline__ unsigned cvt_pk_bf16(float lo, float hi) {
  unsigned r;
  asm("v_cvt_pk_bf16_f32 %0, %1, %2" : "=v"(r) : "v"(lo), "v"(hi));
  return r;
}
__device__ __forceinline__ bf16x8 pack_bf16x8(const float v[8]) {
  union { unsigned u[4]; bf16x8 b; } r;
#pragma unroll
  for (int k = 0; k < 4; ++k) r.u[k] = cvt_pk_bf16(v[2 * k], v[2 * k + 1]);
  return r.b;
}

// Store one 16x16 C-tile (f32x4 per lane) into swizzled bf16 LDS [R][256]
// (row stride 512B). byte ^= (row&7)<<4.
__device__ __forceinline__ void store_tile(short* hs, int l, int mi, int nb,
                                           f32x4 v) {
  const int lm = l & 15, g = l >> 4;
#pragma unroll
  for (int i = 0; i < 4; ++i) {
    const float part = __shfl_xor(v[i], 1);
    if ((l & 1) == 0) {
      const int row = mi * 16 + g * 4 + i;
      const int col = nb + lm;  // even
      const int off = (row * 512 + col * 2) ^ ((row & 7) << 4);
      *(unsigned*)((char*)hs + off) = cvt_pk_bf16(v[i], part);
    }
  }
}

// GEMM from swizzled bf16 LDS tile (row stride AST bytes) x packed W.
template <int MI, int NT, int KC, int AST>
__device__ __forceinline__ void gemm_lds(const short* __restrict__ Wp,
                                         int Ncols, const short* hs, int n0,
                                         int l, f32x4 acc[MI][NT]) {
  const int lm = l & 15, g = l >> 4;
#pragma unroll
  for (int kc = 0; kc < KC; ++kc) {
    bf16x8 a[MI];
#pragma unroll
    for (int mi = 0; mi < MI; ++mi) {
      const int row = mi * 16 + lm;
      const int off = (row * AST + kc * 64 + g * 16) ^ ((row & 7) << 4);
      a[mi] = *(const bf16x8*)((const char*)hs + off);
    }
#pragma unroll
    for (int ni = 0; ni < NT; ++ni) {
      const int n = n0 + ni * 16 + lm;
      bf16x8 b = *(const bf16x8*)(Wp + ((size_t)kc * Ncols + n) * 32 + g * 8);
#pragma unroll
      for (int mi = 0; mi < MI; ++mi)
        acc[mi][ni] =
            __builtin_amdgcn_mfma_f32_16x16x32_bf16(a[mi], b, acc[mi][ni], 0, 0, 0);
    }
  }
}

// ---------------------------------------------------------------------------
// Fused weight packing: all fp32 weights -> bf16 packed layouts, ONE kernel.
// pack_elem: [K][N] (cnt stacked) -> Wp[k/32][n][k%32].
// ---------------------------------------------------------------------------
__device__ __forceinline__ void pack_elem(const float* __restrict__ src,
                                          short* __restrict__ dst, int K,
                                          int N, size_t i) {
  const size_t mat = i / ((size_t)K * N);
  const int rem = (int)(i - mat * (size_t)K * N);
  const int k = rem / N, n = rem - k * N;
  dst[mat * (size_t)K * N + ((size_t)(k >> 5) * N + n) * 32 + (k & 31)] =
      f2bs(src[i]);
}

__global__ __launch_bounds__(256) void pack_all(
    const float* __restrict__ s0, short* __restrict__ d0,   // en_W1 256x256
    const float* __restrict__ s1, short* __restrict__ d1,   // ee_W1 256x256
    const float* __restrict__ s2, short* __restrict__ d2,   // pe_W0 4x768x256
    const float* __restrict__ s3, short* __restrict__ d3,   // pe_W1 4x256x256
    const float* __restrict__ s4, short* __restrict__ d4,   // pn_W0 4x512x256
    const float* __restrict__ s5, short* __restrict__ d5,   // pn_W1 4x256x256
    const float* __restrict__ s6, short* __restrict__ d6,   // dn_W0 256x256
    const float* __restrict__ s7, short* __restrict__ d7,   // dn_W1 256x128
    const float* __restrict__ p0s, short* __restrict__ p0d, // en_W0 pad K=3
    const float* __restrict__ p1s, short* __restrict__ p1d) // ee_W0 pad K=4
{
  size_t i = (size_t)blockIdx.x * 256 + threadIdx.x;
  if (i < 65536) { pack_elem(s0, d0, 256, 256, i); return; } i -= 65536;
  if (i < 65536) { pack_elem(s1, d1, 256, 256, i); return; } i -= 65536;
  if (i < 786432) { pack_elem(s2, d2, 768, 256, i); return; } i -= 786432;
  if (i < 262144) { pack_elem(s3, d3, 256, 256, i); return; } i -= 262144;
  if (i < 524288) { pack_elem(s4, d4, 512, 256, i); return; } i -= 524288;
  if (i < 262144) { pack_elem(s5, d5, 256, 256, i); return; } i -= 262144;
  if (i < 65536) { pack_elem(s6, d6, 256, 256, i); return; } i -= 65536;
  if (i < 32768) { pack_elem(s7, d7, 256, 128, i); return; } i -= 32768;
  if (i < 8192) {
    const int n = (int)i >> 5, k = (int)i & 31;
    p0d[i] = (k < 3) ? f2bs(p0s[k * 256 + n]) : (short)0;
    return;
  }
  i -= 8192;
  if (i < 8192) {
    const int n = (int)i >> 5, k = (int)i & 31;
    p1d[i] = (k < 4) ? f2bs(p1s[k * 256 + n]) : (short)0;
  }
}
// total elements = 2064384 + 16384 = 2080768 = 8128 * 256

// ---------------------------------------------------------------------------
// Async staging: [32][256] bf16 tile (16KB) from 32 consecutive global rows.
// Source byte pre-XOR'd with (row&7)<<4; LDS linear (m173 both-sides rule).
// ---------------------------------------------------------------------------
__device__ __forceinline__ void stage_tile256(const short* __restrict__ src0,
                                              short* As, int w, int l) {
#pragma unroll
  for (int i = 0; i < 4; ++i) {
    const int rbase = w * 8 + i * 2;
    const int r = rbase + (l >> 5);
    const int boff = ((l & 31) * 16) ^ ((r & 7) << 4);
    gload16((const char*)(src0 + (size_t)r * L) + boff, As + rbase * 256);
  }
}

// BM=16 variant: stage cols 0..255 (bytes [0,512) of each 1024B row) of a
// [16][512] tile; lanes 0..31 active. Upper half produced in-kernel.
__device__ __forceinline__ void stage_nodes_half16(
    const short* __restrict__ a_src, short* As, int w, int l, int n0) {
#pragma unroll
  for (int i = 0; i < 4; ++i) {
    const int r = w * 4 + i;
    if (l < 32) {
      const int cb = (l * 16) ^ ((r & 7) << 4);
      gload16((const char*)(a_src + (size_t)(n0 + r) * L) + cb, As + r * 512);
    }
  }
}

// ---------------------------------------------------------------------------
// CSR build (deterministic: per-node lists sorted ascending by edge id).
// elist becomes the edge PERMUTATION: edge state lives in CSR order.
// ---------------------------------------------------------------------------
__global__ void csr_hist(const int* __restrict__ recv, int* __restrict__ deg) {
  const int e = blockIdx.x * 256 + threadIdx.x;
  atomicAdd(&deg[recv[e]], 1);
}
__global__ __launch_bounds__(256) void csr_scan(const int* __restrict__ deg,
                                                int* __restrict__ start,
                                                int* __restrict__ cursor) {
  __shared__ int part[256];
  const int t = threadIdx.x;
  int s = 0;
  for (int i = 0; i < NN / 256; ++i) s += deg[t * (NN / 256) + i];
  part[t] = s;
  __syncthreads();
  if (t == 0) {
    int acc = 0;
    for (int i = 0; i < 256; ++i) {
      const int v = part[i];
      part[i] = acc;
      acc += v;
    }
  }
  __syncthreads();
  int acc = part[t];
  for (int i = 0; i < NN / 256; ++i) {
    const int n = t * (NN / 256) + i;
    start[n] = acc;
    cursor[n] = acc;
    acc += deg[n];
  }
  if (t == 255) start[NN] = acc;
}
__global__ void csr_scatter(const int* __restrict__ recv,
                            int* __restrict__ cursor, int* __restrict__ elist) {
  const int e = blockIdx.x * 256 + threadIdx.x;
  const int p = atomicAdd(&cursor[recv[e]], 1);
  elist[p] = e;
}
__global__ void csr_sort(const int* __restrict__ start, int* __restrict__ elist) {
  const int n = blockIdx.x * blockDim.x + threadIdx.x;
  if (n >= NN) return;
  const int b = start[n], e = start[n + 1];
  for (int i = b + 1; i < e; ++i) {
    const int v = elist[i];
    int j = i - 1;
    while (j >= b && elist[j] > v) {
      elist[j + 1] = elist[j];
      --j;
    }
    elist[j + 1] = v;
  }
}
// permuted sender/receiver arrays: s/r of the edge at permuted position p
__global__ void permute_se(const int* __restrict__ elist,
                           const int* __restrict__ senders,
                           const int* __restrict__ receivers,
                           int* __restrict__ sn_p, int* __restrict__ rc_p) {
  const int p = blockIdx.x * 256 + threadIdx.x;
  const int e = elist[p];
  sn_p[p] = senders[e];
  rc_p[p] = receivers[e];
}

// ---------------------------------------------------------------------------
// Epilogue LN helpers
// ---------------------------------------------------------------------------
__device__ __forceinline__ void ln_row(const short* smem, int row, int seg,
                                       const float lsv[16], const float lbv[16],
                                       float ne[16]) {
  const int off0 = (row * 512 + seg * 16) ^ ((row & 7) << 4);
  const int off1 = (row * 512 + 256 + seg * 16) ^ ((row & 7) << 4);
  const bf16x8 y0 = *(const bf16x8*)((const char*)smem + off0);
  const bf16x8 y1 = *(const bf16x8*)((const char*)smem + off1);
  float v[16];
#pragma unroll
  for (int k = 0; k < 8; ++k) {
    v[k] = bs2f(y0[k]);
    v[8 + k] = bs2f(y1[k]);
  }
  float s = 0.f;
#pragma unroll
  for (int k = 0; k < 16; ++k) s += v[k];
#pragma unroll
  for (int o = 1; o < 16; o <<= 1) s += __shfl_xor(s, o);
  const float mu = s * (1.f / 256.f);
  float sq = 0.f;
#pragma unroll
  for (int k = 0; k < 16; ++k) {
    const float d = v[k] - mu;
    sq += d * d;
  }
#pragma unroll
  for (int o = 1; o < 16; o <<= 1) sq += __shfl_xor(sq, o);
  const float rstd = rsqrtf(sq * (1.f / 256.f) + 1e-6f);
#pragma unroll
  for (int k = 0; k < 16; ++k) ne[k] = (v[k] - mu) * rstd * lsv[k] + lbv[k];
}

__device__ __forceinline__ void load16(const float* __restrict__ p, int seg,
                                       float d[16]) {
  const float4 a0 = *(const float4*)(p + seg * 8);
  const float4 a1 = *(const float4*)(p + seg * 8 + 4);
  const float4 a2 = *(const float4*)(p + 128 + seg * 8);
  const float4 a3 = *(const float4*)(p + 128 + seg * 8 + 4);
  d[0] = a0.x; d[1] = a0.y; d[2] = a0.z; d[3] = a0.w;
  d[4] = a1.x; d[5] = a1.y; d[6] = a1.z; d[7] = a1.w;
  d[8] = a2.x; d[9] = a2.y; d[10] = a2.z; d[11] = a2.w;
  d[12] = a3.x; d[13] = a3.y; d[14] = a3.z; d[15] = a3.w;
}

// ---------------------------------------------------------------------------
// Edge step (CSR-ordered edges): h = relu(edges@W0_e + NS[snd] + NR[rcv] +
// b0); y = h@W1 + b1; LN -> edges_b += ne (old stashed from LDS); new_e = ne.
// Receivers are non-decreasing -> NR gathers are L1/L2-local.  32KB LDS.
// launch_bounds (256,4): (256,5) squeezed VGPR to 48 and broke the early
// NS/NR gather overlap (r12); two-tile pipelining spilled to scratch (r16).
// ---------------------------------------------------------------------------
__global__ __launch_bounds__(256, 4) void edge_step_mfma(
    const short* __restrict__ NSb, const short* __restrict__ NRb,
    short* __restrict__ edges_b, short* __restrict__ new_e,
    const int* __restrict__ senders, const int* __restrict__ receivers,
    const short* __restrict__ W0p, const float* __restrict__ b0,
    const short* __restrict__ W1p, const float* __restrict__ b1,
    const float* __restrict__ ls, const float* __restrict__ lb) {
  __shared__ char smem[32768];
  short* As = (short*)smem;               // [32][256] staged edges; later h
  short* nsrB = (short*)(smem + 16384);   // [32][256] bf16 NS+NR; later y
  const int t = threadIdx.x, w = t >> 6, l = t & 63;
  const int lm = l & 15, g = l >> 4;
  const int tr = t >> 4, seg = t & 15;
  const int e0 = blockIdx.x * 32;

  // E1: indices + self-row staging
  const int sn0 = senders[e0 + tr], rc0 = receivers[e0 + tr];
  const int sn1 = senders[e0 + 16 + tr], rc1 = receivers[e0 + 16 + tr];
  stage_tile256(edges_b + (size_t)e0 * L, As, w, l);
  __syncthreads();

  // E2: NSR gathers (issued first), layer-1 MFMA, old-edge stash,
  //     NSR sum -> bf16 LDS
  bf16x8 gn[2][2], gr[2][2];
  {
    const short* p0 = NSb + (size_t)sn0 * L + seg * 8;
    gn[0][0] = *(const bf16x8*)p0;
    gn[0][1] = *(const bf16x8*)(p0 + 128);
    const short* p1 = NSb + (size_t)sn1 * L + seg * 8;
    gn[1][0] = *(const bf16x8*)p1;
    gn[1][1] = *(const bf16x8*)(p1 + 128);
    const short* q0 = NRb + (size_t)rc0 * L + seg * 8;
    gr[0][0] = *(const bf16x8*)q0;
    gr[0][1] = *(const bf16x8*)(q0 + 128);
    const short* q1 = NRb + (size_t)rc1 * L + seg * 8;
    gr[1][0] = *(const bf16x8*)q1;
    gr[1][1] = *(const bf16x8*)(q1 + 128);
  }

  f32x4 acc[2][4] = {};
  gemm_lds<2, 4, 8, 512>(W0p, L, As, w * 64, l, acc);

  bf16x8 old0[2], old1[2];
#pragma unroll
  for (int p = 0; p < 2; ++p) {
    const int row = p * 16 + tr;
    old0[p] = *(const bf16x8*)((const char*)As +
                               ((row * 512 + seg * 16) ^ ((row & 7) << 4)));
    old1[p] = *(const bf16x8*)((const char*)As +
                               ((row * 512 + 256 + seg * 16) ^ ((row & 7) << 4)));
  }

#pragma unroll
  for (int p = 0; p < 2; ++p) {
    const int row = p * 16 + tr;
    float s[16];
#pragma unroll
    for (int k = 0; k < 8; ++k) {
      s[k] = bs2f(gn[p][0][k]) + bs2f(gr[p][0][k]);
      s[8 + k] = bs2f(gn[p][1][k]) + bs2f(gr[p][1][k]);
    }
    const int off0 = (row * 512 + seg * 16) ^ ((row & 7) << 4);
    const int off1 = (row * 512 + 256 + seg * 16) ^ ((row & 7) << 4);
    *(bf16x8*)((char*)nsrB + off0) = pack_bf16x8(s);
    *(bf16x8*)((char*)nsrB + off1) = pack_bf16x8(s + 8);
  }
  __syncthreads();

  // E3: h-build (acc + b0 + NSR, relu) -> h into As
#pragma unroll
  for (int ni = 0; ni < 4; ++ni) {
    const float bia = b0[w * 64 + ni * 16 + lm];
    const int col = w * 64 + ni * 16 + lm;
#pragma unroll
    for (int mi = 0; mi < 2; ++mi) {
      f32x4 v = acc[mi][ni];
#pragma unroll
      for (int i = 0; i < 4; ++i) {
        const int row = mi * 16 + g * 4 + i;
        const int noff = (row * 512 + col * 2) ^ ((row & 7) << 4);
        v[i] = fmaxf(v[i] + bia + bs2f(*(const short*)((const char*)nsrB + noff)),
                     0.f);
      }
      store_tile(As, l, mi, w * 64 + ni * 16, v);
    }
  }
  __syncthreads();

  // E4+E5: layer 2, y into nsrB region (nsr consumed at E3)
  f32x4 acc2[2][4] = {};
  gemm_lds<2, 4, 8, 512>(W1p, L, As, w * 64, l, acc2);
#pragma unroll
  for (int ni = 0; ni < 4; ++ni) {
    const float bia = b1[w * 64 + ni * 16 + lm];
#pragma unroll
    for (int mi = 0; mi < 2; ++mi) {
      f32x4 v = acc2[mi][ni];
#pragma unroll
      for (int i = 0; i < 4; ++i) v[i] += bia;
      store_tile(nsrB, l, mi, w * 64 + ni * 16, v);
    }
  }
  __syncthreads();

  // E6: LN + residual + vector stores
  float lsv[16], lbv[16];
  load16(ls, seg, lsv);
  load16(lb, seg, lbv);
#pragma unroll
  for (int p = 0; p < 2; ++p) {
    const int row = p * 16 + tr;
    float ne[16];
    ln_row(nsrB, row, seg, lsv, lbv, ne);
    const size_t e = (size_t)(e0 + row);
    *(bf16x8*)(new_e + e * L + seg * 8) = pack_bf16x8(ne);
    *(bf16x8*)(new_e + e * L + 128 + seg * 8) = pack_bf16x8(ne + 8);
    float r0[8], r1[8];
#pragma unroll
    for (int k = 0; k < 8; ++k) {
      r0[k] = bs2f(old0[p][k]) + ne[k];
      r1[k] = bs2f(old1[p][k]) + ne[8 + k];
    }
    *(bf16x8*)(edges_b + e * L + seg * 8) = pack_bf16x8(r0);
    *(bf16x8*)(edges_b + e * L + 128 + seg * 8) = pack_bf16x8(r1);
  }
}

// ---------------------------------------------------------------------------
// Node step (BM=16, fused aggregation + proj): X=[nodes_b | agg] where agg
// streams CONTIGUOUS new_e rows [start[n],start[n+1]) (CSR-ordered edges;
// same summation order as before -> bit-identical).
// ---------------------------------------------------------------------------
__global__ __launch_bounds__(256, 4) void node_step_mfma(
    float* __restrict__ nodes_f, short* __restrict__ nodes_b,
    const short* __restrict__ new_e, const int* __restrict__ start,
    const short* __restrict__ W0p, const float* __restrict__ b0,
    const short* __restrict__ W1p, const float* __restrict__ b1,
    const float* __restrict__ ls, const float* __restrict__ lb,
    const short* __restrict__ W0nS, const short* __restrict__ W0nR,
    short* __restrict__ NSb, short* __restrict__ NRb) {
  __shared__ char smem[16384];
  short* As = (short*)smem;            // [16][512] staging (16KB)
  short* hb = (short*)smem;            // h [16][256] overlays first 8KB
  short* yb = (short*)(smem + 8192);   // y second 8KB
  const int t = threadIdx.x, w = t >> 6, l = t & 63;
  const int lm = l & 15;
  const int tr = t >> 4, seg = t & 15;
  const int n0 = blockIdx.x * 16;

  // stage nodes half (async) ...
  stage_nodes_half16(nodes_b, As, w, l, n0);

  // ... while aggregating contiguous new_e rows into the agg half
  {
    const int grp = t >> 5, lc = t & 31;
#pragma unroll
    for (int i = 0; i < 2; ++i) {
      const int r = grp * 2 + i;
      const int n = n0 + r;
      const int b = start[n], e = start[n + 1];
      float acc[8] = {0.f, 0.f, 0.f, 0.f, 0.f, 0.f, 0.f, 0.f};
      for (int j = b; j < e; ++j) {
        const bf16x8 v = *(const bf16x8*)(new_e + (size_t)j * L + lc * 8);
#pragma unroll
        for (int k = 0; k < 8; ++k) acc[k] += bs2f(v[k]);
      }
      const int off = (r * 1024 + 512 + lc * 16) ^ ((r & 7) << 4);
      *(bf16x8*)((char*)As + off) = pack_bf16x8(acc);
    }
  }
  __syncthreads();

  f32x4 acc[1][4] = {};
  gemm_lds<1, 4, 16, 1024>(W0p, L, As, w * 64, l, acc);
  __syncthreads();

#pragma unroll
  for (int ni = 0; ni < 4; ++ni) {
    const float bia = b0[w * 64 + ni * 16 + lm];
    f32x4 v = acc[0][ni];
#pragma unroll
    for (int i = 0; i < 4; ++i) v[i] = fmaxf(v[i] + bia, 0.f);
    store_tile(hb, l, 0, w * 64 + ni * 16, v);
  }
  __syncthreads();

  f32x4 acc2[1][4] = {};
  gemm_lds<1, 4, 8, 512>(W1p, L, hb, w * 64, l, acc2);
  __syncthreads();
#pragma unroll
  for (int ni = 0; ni < 4; ++ni) {
    const float bia = b1[w * 64 + ni * 16 + lm];
    f32x4 v = acc2[0][ni];
#pragma unroll
    for (int i = 0; i < 4; ++i) v[i] += bia;
    store_tile(yb, l, 0, w * 64 + ni * 16, v);
  }
  __syncthreads();

  float lsv[16], lbv[16];
  load16(ls, seg, lsv);
  load16(lb, seg, lbv);
  {
    const int row = tr;  // 0..15
    float ne[16];
    ln_row(yb, row, seg, lsv, lbv, ne);
    const size_t n = (size_t)(n0 + row);
    float* nf = nodes_f + n * L;
    float fv[16];
    load16(nf, seg, fv);
    float nv[16];
#pragma unroll
    for (int k = 0; k < 16; ++k) nv[k] = fv[k] + ne[k];
    *(float4*)(nf + seg * 8) = make_float4(nv[0], nv[1], nv[2], nv[3]);
    *(float4*)(nf + seg * 8 + 4) = make_float4(nv[4], nv[5], nv[6], nv[7]);
    *(float4*)(nf + 128 + seg * 8) = make_float4(nv[8], nv[9], nv[10], nv[11]);
    *(float4*)(nf + 128 + seg * 8 + 4) = make_float4(nv[12], nv[13], nv[14], nv[15]);
    const bf16x8 nb0 = pack_bf16x8(nv);
    const bf16x8 nb1 = pack_bf16x8(nv + 8);
    *(bf16x8*)(nodes_b + n * L + seg * 8) = nb0;
    *(bf16x8*)(nodes_b + n * L + 128 + seg * 8) = nb1;
    // also place the new node row into hb (swizzled) for the fused proj
    const int off0 = (row * 512 + seg * 16) ^ ((row & 7) << 4);
    const int off1 = (row * 512 + 256 + seg * 16) ^ ((row & 7) << 4);
    *(bf16x8*)((char*)hb + off0) = nb0;
    *(bf16x8*)((char*)hb + off1) = nb1;
  }

  if (W0nS == nullptr) return;
  __syncthreads();

  // fused proj, sender panel
  {
    f32x4 pa[1][4] = {};
    gemm_lds<1, 4, 8, 512>(W0nS, L, hb, w * 64, l, pa);
#pragma unroll
    for (int ni = 0; ni < 4; ++ni)
      store_tile(yb, l, 0, w * 64 + ni * 16, pa[0][ni]);
    __syncthreads();
    {
      const int row = tr;
      const int off0 = (row * 512 + seg * 16) ^ ((row & 7) << 4);
      const int off1 = (row * 512 + 256 + seg * 16) ^ ((row & 7) << 4);
      *(bf16x8*)(NSb + (size_t)(n0 + row) * L + seg * 8) =
          *(const bf16x8*)((const char*)yb + off0);
      *(bf16x8*)(NSb + (size_t)(n0 + row) * L + 128 + seg * 8) =
          *(const bf16x8*)((const char*)yb + off1);
    }
  }
  __syncthreads();

  // fused proj, receiver panel
  {
    f32x4 pa[1][4] = {};
    gemm_lds<1, 4, 8, 512>(W0nR, L, hb, w * 64, l, pa);
#pragma unroll
    for (int ni = 0; ni < 4; ++ni)
      store_tile(yb, l, 0, w * 64 + ni * 16, pa[0][ni]);
    __syncthreads();
    {
      const int row = tr;
      const int off0 = (row * 512 + seg * 16) ^ ((row & 7) << 4);
      const int off1 = (row * 512 + 256 + seg * 16) ^ ((row & 7) << 4);
      *(bf16x8*)(NRb + (size_t)(n0 + row) * L + seg * 8) =
          *(const bf16x8*)((const char*)yb + off0);
      *(bf16x8*)(NRb + (size_t)(n0 + row) * L + 128 + seg * 8) =
          *(const bf16x8*)((const char*)yb + off1);
    }
  }
}

// ---------------------------------------------------------------------------
// Embedder: layer1 via zero-padded K=32 MFMA -> h in LDS -> MFMA layer2 ->
// LN -> dst. WF32: also write fp32 master. gidx: optional row gather
// (CSR-ordered edge features). PROJ: also emit step-0 NS/NR projections
// from the freshly-embedded node tile (fused proj; bit-identical to the
// old standalone proj kernel since it consumes the same bf16 LN output).
// ---------------------------------------------------------------------------
template <int K1, bool WF32, bool PROJ>
__global__ __launch_bounds__(256) void embed_mfma(
    const float* __restrict__ x, const int* __restrict__ gidx,
    const short* __restrict__ W0p, const float* __restrict__ b0,
    const short* __restrict__ W1p, const float* __restrict__ b1,
    const float* __restrict__ ls, const float* __restrict__ lb,
    float* __restrict__ dst_f, short* __restrict__ dst_b,
    const short* __restrict__ W0nS, const short* __restrict__ W0nR,
    short* __restrict__ NSb, short* __restrict__ NRb) {
  __shared__ short hs[64 * 256];
  __shared__ short xsb[64 * 32];
  __shared__ short ps[PROJ ? 64 * 256 : 16];  // proj output buffer
  const int t = threadIdx.x, w = t >> 6, l = t & 63;
  const int lm = l & 15, g = l >> 4;
  const int tr = t >> 4, seg = t & 15;
  const int r0 = blockIdx.x * 64;

  if (t < 64) {
    const size_t srow = gidx ? (size_t)gidx[r0 + t] : (size_t)(r0 + t);
    const float* xr = x + srow * K1;
    float v[8] = {0.f, 0.f, 0.f, 0.f, 0.f, 0.f, 0.f, 0.f};
#pragma unroll
    for (int k = 0; k < K1; ++k) v[k] = xr[k];
    bf16x8 z;
#pragma unroll
    for (int k = 0; k < 8; ++k) z[k] = 0;
    char* rb = (char*)xsb + t * 64;
    *(bf16x8*)(rb + (0 ^ ((t & 3) << 4))) = pack_bf16x8(v);
#pragma unroll
    for (int gi = 1; gi < 4; ++gi) *(bf16x8*)(rb + ((gi * 16) ^ ((t & 3) << 4))) = z;
  }
  __syncthreads();

  f32x4 acc[4][4] = {};
  {
    bf16x8 a[4];
#pragma unroll
    for (int mi = 0; mi < 4; ++mi) {
      const int row = mi * 16 + lm;
      a[mi] = *(const bf16x8*)((const char*)xsb + row * 64 +
                               ((g * 16) ^ ((row & 3) << 4)));
    }
#pragma unroll
    for (int ni = 0; ni < 4; ++ni) {
      const int n = w * 64 + ni * 16 + lm;
      bf16x8 b = *(const bf16x8*)(W0p + n * 32 + g * 8);
#pragma unroll
      for (int mi = 0; mi < 4; ++mi)
        acc[mi][ni] =
            __builtin_amdgcn_mfma_f32_16x16x32_bf16(a[mi], b, acc[mi][ni], 0, 0, 0);
    }
  }
#pragma unroll
  for (int ni = 0; ni < 4; ++ni) {
    const float bia = b0[w * 64 + ni * 16 + lm];
#pragma unroll
    for (int mi = 0; mi < 4; ++mi) {
      f32x4 v = acc[mi][ni];
#pragma unroll
      for (int i = 0; i < 4; ++i) v[i] = fmaxf(v[i] + bia, 0.f);
      store_tile(hs, l, mi, w * 64 + ni * 16, v);
    }
  }
  __syncthreads();

  f32x4 acc2[4][4] = {};
  gemm_lds<4, 4, 8, 512>(W1p, L, hs, w * 64, l, acc2);
  __syncthreads();
#pragma unroll
  for (int ni = 0; ni < 4; ++ni) {
    const float bia = b1[w * 64 + ni * 16 + lm];
#pragma unroll
    for (int mi = 0; mi < 4; ++mi) {
      f32x4 v = acc2[mi][ni];
#pragma unroll
      for (int i = 0; i < 4; ++i) v[i] += bia;
      store_tile(hs, l, mi, w * 64 + ni * 16, v);
    }
  }
  __syncthreads();

  float lsv[16], lbv[16];
  load16(ls, seg, lsv);
  load16(lb, seg, lbv);
#pragma unroll
  for (int p = 0; p < 4; ++p) {
    const int row = p * 16 + tr;
    float ne[16];
    ln_row(hs, row, seg, lsv, lbv, ne);
    const size_t n = (size_t)(r0 + row);
    const bf16x8 nb0 = pack_bf16x8(ne);
    const bf16x8 nb1 = pack_bf16x8(ne + 8);
    *(bf16x8*)(dst_b + n * L + seg * 8) = nb0;
    *(bf16x8*)(dst_b + n * L + 128 + seg * 8) = nb1;
    if (WF32) {
      float* df = dst_f + n * L;
      *(float4*)(df + seg * 8) = make_float4(ne[0], ne[1], ne[2], ne[3]);
      *(float4*)(df + seg * 8 + 4) = make_float4(ne[4], ne[5], ne[6], ne[7]);
      *(float4*)(df + 128 + seg * 8) = make_float4(ne[8], ne[9], ne[10], ne[11]);
      *(float4*)(df + 128 + seg * 8 + 4) =
          make_float4(ne[12], ne[13], ne[14], ne[15]);
    }
    if (PROJ) {
      // place LN'd bf16 node row back into hs (swizzled, same slots this
      // thread just read) for the proj GEMMs
      const int off0 = (row * 512 + seg * 16) ^ ((row & 7) << 4);
      const int off1 = (row * 512 + 256 + seg * 16) ^ ((row & 7) << 4);
      *(bf16x8*)((char*)hs + off0) = nb0;
      *(bf16x8*)((char*)hs + off1) = nb1;
    }
  }

  if constexpr (PROJ) {
    __syncthreads();
    // sender panel
    {
      f32x4 pa[4][4] = {};
      gemm_lds<4, 4, 8, 512>(W0nS, L, hs, w * 64, l, pa);
#pragma unroll
      for (int ni = 0; ni < 4; ++ni)
#pragma unroll
        for (int mi = 0; mi < 4; ++mi)
          store_tile(ps, l, mi, w * 64 + ni * 16, pa[mi][ni]);
      __syncthreads();
#pragma unroll
      for (int p = 0; p < 4; ++p) {
        const int row = p * 16 + tr;
        const int off0 = (row * 512 + seg * 16) ^ ((row & 7) << 4);
        const int off1 = (row * 512 + 256 + seg * 16) ^ ((row & 7) << 4);
        *(bf16x8*)(NSb + (size_t)(r0 + row) * L + seg * 8) =
            *(const bf16x8*)((const char*)ps + off0);
        *(bf16x8*)(NSb + (size_t)(r0 + row) * L + 128 + seg * 8) =
            *(const bf16x8*)((const char*)ps + off1);
      }
    }
    __syncthreads();
    // receiver panel
    {
      f32x4 pa[4][4] = {};
      gemm_lds<4, 4, 8, 512>(W0nR, L, hs, w * 64, l, pa);
#pragma unroll
      for (int ni = 0; ni < 4; ++ni)
#pragma unroll
        for (int mi = 0; mi < 4; ++mi)
          store_tile(ps, l, mi, w * 64 + ni * 16, pa[mi][ni]);
      __syncthreads();
#pragma unroll
      for (int p = 0; p < 4; ++p) {
        const int row = p * 16 + tr;
        const int off0 = (row * 512 + seg * 16) ^ ((row & 7) << 4);
        const int off1 = (row * 512 + 256 + seg * 16) ^ ((row & 7) << 4);
        *(bf16x8*)(NRb + (size_t)(r0 + row) * L + seg * 8) =
            *(const bf16x8*)((const char*)ps + off0);
        *(bf16x8*)(NRb + (size_t)(r0 + row) * L + 128 + seg * 8) =
            *(const bf16x8*)((const char*)ps + off1);
      }
    }
  }
}

// ---------------------------------------------------------------------------
// Decoder: nodes_b (256 bf16) -> MFMA 256 relu -> MFMA 128 -> out (fp32)
// ---------------------------------------------------------------------------
__global__ __launch_bounds__(256) void decoder_mfma(
    const short* __restrict__ nodes_b, const short* __restrict__ W0p,
    const float* __restrict__ b0, const short* __restrict__ W1p,
    const float* __restrict__ b1, float* __restrict__ out) {
  __shared__ short hs[64 * 256];
  const int t = threadIdx.x, w = t >> 6, l = t & 63;
  const int lm = l & 15, g = l >> 4;
  const int n0 = blockIdx.x * 64;

  const short* baseA[4];
#pragma unroll
  for (int mi = 0; mi < 4; ++mi)
    baseA[mi] = nodes_b + (size_t)(n0 + mi * 16 + lm) * L;

  f32x4 acc[4][4] = {};
#pragma unroll
  for (int kc = 0; kc < 8; ++kc) {
    const int koff = kc * 32 + g * 8;
    bf16x8 a[4];
#pragma unroll
    for (int mi = 0; mi < 4; ++mi) a[mi] = *(const bf16x8*)(baseA[mi] + koff);
#pragma unroll
    for (int ni = 0; ni < 4; ++ni) {
      const int n = w * 64 + ni * 16 + lm;
      bf16x8 b = *(const bf16x8*)(W0p + ((size_t)kc * L + n) * 32 + g * 8);
#pragma unroll
      for (int mi = 0; mi < 4; ++mi)
        acc[mi][ni] = __builtin_amdgcn_mfma_f32_16x16x32_bf16(a[mi], b,
                                                             acc[mi][ni],
                                                             0, 0, 0);
    }
  }
#pragma unroll
  for (int ni = 0; ni < 4; ++ni) {
    const float bia = b0[w * 64 + ni * 16 + lm];
#pragma unroll
    for (int mi = 0; mi < 4; ++mi) {
      f32x4 v = acc[mi][ni];
#pragma unroll
      for (int i = 0; i < 4; ++i) v[i] = fmaxf(v[i] + bia, 0.f);
      store_tile(hs, l, mi, w * 64 + ni * 16, v);
    }
  }
  __syncthreads();

  f32x4 acc2[4][2] = {};
  gemm_lds<4, 2, 8, 512>(W1p, OUTD, hs, w * 32, l, acc2);

  float b14[2];
#pragma unroll
  for (int ni = 0; ni < 2; ++ni) b14[ni] = b1[w * 32 + ni * 16 + lm];
#pragma unroll
  for (int mi = 0; mi < 4; ++mi)
#pragma unroll
    for (int ni = 0; ni < 2; ++ni)
#pragma unroll
      for (int i = 0; i < 4; ++i) {
        const int row = n0 + mi * 16 + g * 4 + i;
        const int col = w * 32 + ni * 16 + lm;
        out[(size_t)row * OUTD + col] = acc2[mi][ni][i] + b14[ni];
      }
}

// ---------------------------------------------------------------------------
extern "C" void kernel_launch(void* const* d_in, const int* in_sizes, int n_in,
                              void* d_out, int out_size, void* d_ws,
                              size_t ws_size, hipStream_t stream) {
  const float* node_feats = (const float*)d_in[0];
  const float* edge_feats = (const float*)d_in[1];
  const int* senders = (const int*)d_in[2];
  const int* receivers = (const int*)d_in[3];
  auto f = [&](int i) { return (const float*)d_in[i]; };

  char* p = (char*)d_ws;
  auto alloc = [&](size_t bytes) {
    char* q = p;
    p += (bytes + 255) & ~(size_t)255;
    return q;
  };
  float* nodes_f = (float*)alloc((size_t)NN * L * 4);
  short* nodes_b = (short*)alloc((size_t)NN * L * 2);
  short* edges_b = (short*)alloc((size_t)NE * L * 2);
  short* new_e = (short*)alloc((size_t)NE * L * 2);
  short* NSb = (short*)alloc((size_t)NN * L * 2);
  short* NRb = (short*)alloc((size_t)NN * L * 2);
  int* deg = (int*)alloc((size_t)NN * 4);
  int* start = (int*)alloc((size_t)(NN + 16) * 4);
  int* cursor = (int*)alloc((size_t)NN * 4);
  int* elist = (int*)alloc((size_t)NE * 4);
  int* sn_p = (int*)alloc((size_t)NE * 4);
  int* rc_p = (int*)alloc((size_t)NE * 4);
  short* en_W0p = (short*)alloc(256 * 32 * 2);
  short* ee_W0p = (short*)alloc(256 * 32 * 2);
  short* en_W1p = (short*)alloc(65536 * 2);
  short* ee_W1p = (short*)alloc(65536 * 2);
  short* pe_W0p = (short*)alloc((size_t)4 * 768 * 256 * 2);
  short* pe_W1p = (short*)alloc((size_t)4 * 65536 * 2);
  short* pn_W0p = (short*)alloc((size_t)4 * 512 * 256 * 2);
  short* pn_W1p = (short*)alloc((size_t)4 * 65536 * 2);
  short* dn_W0p = (short*)alloc(65536 * 2);
  short* dn_W1p = (short*)alloc(32768 * 2);

  // CSR build; elist = stable (receiver, edge-id) order = edge permutation
  hipMemsetAsync(deg, 0, (size_t)NN * 4, stream);
  csr_hist<<<NE / 256, 256, 0, stream>>>(receivers, deg);
  csr_scan<<<1, 256, 0, stream>>>(deg, start, cursor);
  csr_scatter<<<NE / 256, 256, 0, stream>>>(receivers, cursor, elist);
  csr_sort<<<NN / 256, 256, 0, stream>>>(start, elist);
  permute_se<<<NE / 256, 256, 0, stream>>>(elist, senders, receivers, sn_p,
                                           rc_p);

  // one fused weight-pack dispatch (2,080,768 elements = 8128 blocks)
  pack_all<<<8128, 256, 0, stream>>>(
      f(6), en_W1p, f(12), ee_W1p, f(16), pe_W0p, f(18), pe_W1p, f(22),
      pn_W0p, f(24), pn_W1p, f(28), dn_W0p, f(30), dn_W1p, f(4), en_W0p,
      f(10), ee_W0p);

  // node embed + fused step-0 NS/NR projection
  embed_mfma<3, true, true><<<NN / 64, 256, 0, stream>>>(
      node_feats, nullptr, en_W0p, f(5), en_W1p, f(7), f(8), f(9), nodes_f,
      nodes_b, pe_W0p + (size_t)8 * 256 * 32, pe_W0p + (size_t)16 * 256 * 32,
      NSb, NRb);
  // edge features gathered into CSR order
  embed_mfma<4, false, false><<<NE / 64, 256, 0, stream>>>(
      edge_feats, elist, ee_W0p, f(11), ee_W1p, f(13), f(14), f(15), nullptr,
      edges_b, nullptr, nullptr, nullptr, nullptr);

  for (int s = 0; s < SSTEPS; ++s) {
    const short* W0s = pe_W0p + (size_t)s * 768 * 256;
    edge_step_mfma<<<NE / 32, 256, 0, stream>>>(
        NSb, NRb, edges_b, new_e, sn_p, rc_p, W0s, f(17) + (size_t)s * 256,
        pe_W1p + (size_t)s * 65536, f(19) + (size_t)s * 256,
        f(20) + (size_t)s * 256, f(21) + (size_t)s * 256);
    const short* W0n = (s + 1 < SSTEPS) ? pe_W0p + (size_t)(s + 1) * 768 * 256
                                        : nullptr;
    node_step_mfma<<<NN / 16, 256, 0, stream>>>(
        nodes_f, nodes_b, new_e, start, pn_W0p + (size_t)s * 512 * 256,
        f(23) + (size_t)s * 256, pn_W1p + (size_t)s * 65536,
        f(25) + (size_t)s * 256, f(26) + (size_t)s * 256,
        f(27) + (size_t)s * 256, W0n ? W0n + (size_t)8 * 256 * 32 : nullptr,
        W0n ? W0n + (size_t)16 * 256 * 32 : nullptr, NSb, NRb);
  }

  decoder_mfma<<<NN / 64, 256, 0, stream>>>(nodes_b, dn_W0p, f(29), dn_W1p,
                                            f(31), (float*)d_out);
}